// Round 1
// baseline (2595.041 us; speedup 1.0000x reference)
//
#include <hip/hip_runtime.h>
#include <hip/hip_bf16.h>

#define BB   4
#define NN   10000
#define EE   160000
#define FIN  256
#define HH   8
#define FO   32
#define CC   256            // H*FO
#define BN   40000          // B*N
#define BE   640000         // B*E

__device__ __forceinline__ float bf2f(unsigned short u) {
    unsigned int v = ((unsigned int)u) << 16;
    return __uint_as_float(v);
}

// ---------------------------------------------------------------------------
// Kernel A: proj = x @ W^T (f32), store proj as bf16, compute per-node
// s_src[h] = proj[n,h,:]·a_src[h], s_trg likewise (f32, shuffle reduce).
// Block: 256 threads, 16 rows per block. Thread t owns output column c=t.
// ---------------------------------------------------------------------------
__global__ __launch_bounds__(256) void k_proj(
    const float* __restrict__ x, const float* __restrict__ Wm,
    const float* __restrict__ a_src, const float* __restrict__ a_trg,
    __hip_bfloat16* __restrict__ proj, float* __restrict__ ssrc,
    float* __restrict__ strg)
{
    __shared__ float xs[16 * FIN];
    const int t = threadIdx.x;
    const int row0 = blockIdx.x * 16;

    // stage 16 rows of x (16*256 f32 = 16 KiB), coalesced float4
    const float4* xg = (const float4*)(x + (size_t)row0 * FIN);
    float4* xsw = (float4*)xs;
#pragma unroll
    for (int i = 0; i < 4; ++i) xsw[i * 256 + t] = xg[i * 256 + t];
    __syncthreads();

    float acc[16];
#pragma unroll
    for (int r = 0; r < 16; ++r) acc[r] = 0.f;

    const float4* w4  = (const float4*)(Wm + (size_t)t * FIN);  // W row c=t
    const float4* xs4 = (const float4*)xs;
    for (int k4 = 0; k4 < FIN / 4; ++k4) {
        float4 w = w4[k4];
#pragma unroll
        for (int r = 0; r < 16; ++r) {
            float4 xv = xs4[r * (FIN / 4) + k4];   // LDS broadcast (uniform addr)
            acc[r] += xv.x * w.x + xv.y * w.y + xv.z * w.z + xv.w * w.w;
        }
    }

    const float as = a_src[t];   // a_src flattened [H*FO] == column c
    const float at = a_trg[t];
    const int  h  = t >> 5;
    const bool writer = (t & 31) == 0;
#pragma unroll
    for (int r = 0; r < 16; ++r) {
        proj[(size_t)(row0 + r) * CC + t] = __float2bfloat16(acc[r]);
        float vs = acc[r] * as;
        float vt = acc[r] * at;
        // reduce across the 32-lane head group (xor masks < 32 stay in group)
#pragma unroll
        for (int off = 16; off >= 1; off >>= 1) {
            vs += __shfl_xor(vs, off);
            vt += __shfl_xor(vt, off);
        }
        if (writer) {
            ssrc[(row0 + r) * HH + h] = vs;
            strg[(row0 + r) * HH + h] = vt;
        }
    }
}

// ---------------------------------------------------------------------------
// Kernel B: per edge, ex[e,h] = mask>0 ? exp(leaky_relu(s_src[src]+s_trg[trg])) : 0
// and den[trg,h] += ex (atomic).
// ---------------------------------------------------------------------------
__global__ __launch_bounds__(256) void k_edge(
    const int* __restrict__ ei, const float* __restrict__ mask,
    const float* __restrict__ ssrc, const float* __restrict__ strg,
    float* __restrict__ ex, float* __restrict__ den)
{
    int e = blockIdx.x * 256 + threadIdx.x;
    if (e >= BE) return;
    int b  = e / EE;
    int le = e - b * EE;
    int src = ei[b * 2 * EE + le]      + b * NN;
    int trg = ei[b * 2 * EE + EE + le] + b * NN;
    float m = mask[e];

    float4 s0 = ((const float4*)(ssrc + (size_t)src * HH))[0];
    float4 s1 = ((const float4*)(ssrc + (size_t)src * HH))[1];
    float4 t0 = ((const float4*)(strg + (size_t)trg * HH))[0];
    float4 t1 = ((const float4*)(strg + (size_t)trg * HH))[1];

    float sc[8] = { s0.x + t0.x, s0.y + t0.y, s0.z + t0.z, s0.w + t0.w,
                    s1.x + t1.x, s1.y + t1.y, s1.z + t1.z, s1.w + t1.w };

    float* exo = ex  + (size_t)e   * HH;
    float* dn  = den + (size_t)trg * HH;
#pragma unroll
    for (int h = 0; h < 8; ++h) {
        float v = sc[h];
        v = v > 0.f ? v : 0.2f * v;            // leaky_relu(0.2)
        v = (m > 0.f) ? __expf(v) : 0.f;       // mask -> exp(-9e15) == 0
        exo[h] = v;
        atomicAdd(dn + h, v);
    }
}

// ---------------------------------------------------------------------------
// Kernel C: per edge (one 64-lane wave), out[trg,:] += proj[src,:] * attn[h]
// attn = ex / (den[trg] + 1e-16). Each lane handles 4 consecutive columns.
// ---------------------------------------------------------------------------
__global__ __launch_bounds__(256) void k_agg(
    const int* __restrict__ ei, const float* __restrict__ mask,
    const __hip_bfloat16* __restrict__ proj, const float* __restrict__ ex,
    const float* __restrict__ den, float* __restrict__ out)
{
    int gid  = blockIdx.x * 256 + threadIdx.x;
    int e    = gid >> 6;
    int lane = gid & 63;
    if (e >= BE) return;
    float m = mask[e];
    if (m <= 0.f) return;                      // masked edge contributes 0
    int b  = e / EE;
    int le = e - b * EE;
    int src = ei[b * 2 * EE + le]      + b * NN;
    int trg = ei[b * 2 * EE + EE + le] + b * NN;

    int h = lane >> 3;                          // (lane*4)/32
    float a = ex[(size_t)e * HH + h] / (den[(size_t)trg * HH + h] + 1e-16f);

    ushort4 p = ((const ushort4*)(proj + (size_t)src * CC))[lane]; // 8B/lane, coalesced
    float* o = out + (size_t)trg * CC + lane * 4;
    atomicAdd(o + 0, bf2f(p.x) * a);
    atomicAdd(o + 1, bf2f(p.y) * a);
    atomicAdd(o + 2, bf2f(p.z) * a);
    atomicAdd(o + 3, bf2f(p.w) * a);
}

// ---------------------------------------------------------------------------
// Kernel D: out = elu(out + bias)
// ---------------------------------------------------------------------------
__global__ __launch_bounds__(256) void k_finish(
    const float* __restrict__ bias, float* __restrict__ out)
{
    int i = blockIdx.x * 256 + threadIdx.x;    // exactly BN*CC threads
    float v = out[i] + bias[i & (CC - 1)];
    out[i] = v > 0.f ? v : __expf(v) - 1.f;
}

// ---------------------------------------------------------------------------
extern "C" void kernel_launch(void* const* d_in, const int* in_sizes, int n_in,
                              void* d_out, int out_size, void* d_ws, size_t ws_size,
                              hipStream_t stream)
{
    const float* x     = (const float*)d_in[0];
    const int*   ei    = (const int*)  d_in[1];
    const float* mask  = (const float*)d_in[2];
    const float* Wm    = (const float*)d_in[3];
    const float* a_src = (const float*)d_in[4];
    const float* a_trg = (const float*)d_in[5];
    const float* bias  = (const float*)d_in[6];
    float* out = (float*)d_out;

    char* ws = (char*)d_ws;
    size_t off = 0;
    __hip_bfloat16* proj = (__hip_bfloat16*)(ws + off); off += (size_t)BN * CC * 2; // 20.48 MB
    float* ssrc = (float*)(ws + off); off += (size_t)BN * HH * 4;                   // 1.28 MB
    float* strg = (float*)(ws + off); off += (size_t)BN * HH * 4;                   // 1.28 MB
    float* ex   = (float*)(ws + off); off += (size_t)BE * HH * 4;                   // 20.48 MB
    float* den  = (float*)(ws + off); off += (size_t)BN * HH * 4;                   // 1.28 MB

    // zero accumulators (harness poisons with 0xAA; we own init every call)
    hipMemsetAsync(out, 0, (size_t)BN * CC * 4, stream);
    hipMemsetAsync(den, 0, (size_t)BN * HH * 4, stream);

    k_proj<<<BN / 16, 256, 0, stream>>>(x, Wm, a_src, a_trg, proj, ssrc, strg);
    k_edge<<<(BE + 255) / 256, 256, 0, stream>>>(ei, mask, ssrc, strg, ex, den);
    k_agg<<<(BE * 64) / 256, 256, 0, stream>>>(ei, mask, proj, ex, den, out);
    k_finish<<<(BN * CC) / 256, 256, 0, stream>>>(bias, out);
}

// Round 2
// 672.081 us; speedup vs baseline: 3.8612x; 3.8612x over previous
//
#include <hip/hip_runtime.h>
#include <hip/hip_bf16.h>

#define BB   4
#define NN   10000
#define EE   160000
#define FIN  256
#define HH   8
#define FO   32
#define CC   256            // H*FO
#define BN   40000          // B*N
#define BE   640000         // B*E

__device__ __forceinline__ float bf2f(unsigned short u) {
    unsigned int v = ((unsigned int)u) << 16;
    return __uint_as_float(v);
}

// ---------------------------------------------------------------------------
// Kernel A: proj = x @ W^T (f32), store proj as bf16, compute per-node
// s_src[h] = proj[n,h,:]·a_src[h], s_trg likewise (f32, shuffle reduce).
// Block: 256 threads, 16 rows per block. Thread t owns output column c=t.
// ---------------------------------------------------------------------------
__global__ __launch_bounds__(256) void k_proj(
    const float* __restrict__ x, const float* __restrict__ Wm,
    const float* __restrict__ a_src, const float* __restrict__ a_trg,
    __hip_bfloat16* __restrict__ proj, float* __restrict__ ssrc,
    float* __restrict__ strg)
{
    __shared__ float xs[16 * FIN];
    const int t = threadIdx.x;
    const int row0 = blockIdx.x * 16;

    const float4* xg = (const float4*)(x + (size_t)row0 * FIN);
    float4* xsw = (float4*)xs;
#pragma unroll
    for (int i = 0; i < 4; ++i) xsw[i * 256 + t] = xg[i * 256 + t];
    __syncthreads();

    float acc[16];
#pragma unroll
    for (int r = 0; r < 16; ++r) acc[r] = 0.f;

    const float4* w4  = (const float4*)(Wm + (size_t)t * FIN);
    const float4* xs4 = (const float4*)xs;
    for (int k4 = 0; k4 < FIN / 4; ++k4) {
        float4 w = w4[k4];
#pragma unroll
        for (int r = 0; r < 16; ++r) {
            float4 xv = xs4[r * (FIN / 4) + k4];
            acc[r] += xv.x * w.x + xv.y * w.y + xv.z * w.z + xv.w * w.w;
        }
    }

    const float as = a_src[t];
    const float at = a_trg[t];
    const int  h  = t >> 5;
    const bool writer = (t & 31) == 0;
#pragma unroll
    for (int r = 0; r < 16; ++r) {
        proj[(size_t)(row0 + r) * CC + t] = __float2bfloat16(acc[r]);
        float vs = acc[r] * as;
        float vt = acc[r] * at;
#pragma unroll
        for (int off = 16; off >= 1; off >>= 1) {
            vs += __shfl_xor(vs, off);
            vt += __shfl_xor(vt, off);
        }
        if (writer) {
            ssrc[(row0 + r) * HH + h] = vs;
            strg[(row0 + r) * HH + h] = vt;
        }
    }
}

// ---------------------------------------------------------------------------
// Kernel B1: deg[trg]++ histogram
// ---------------------------------------------------------------------------
__global__ __launch_bounds__(256) void k_count(
    const int* __restrict__ ei, int* __restrict__ deg)
{
    int e = blockIdx.x * 256 + threadIdx.x;
    if (e >= BE) return;
    int b  = e / EE;
    int le = e - b * EE;
    int trg = ei[b * 2 * EE + EE + le] + b * NN;
    atomicAdd(&deg[trg], 1);
}

// ---------------------------------------------------------------------------
// Kernel B2: single-block exclusive scan over deg[BN] -> rowptr, cursor
// ---------------------------------------------------------------------------
__global__ __launch_bounds__(256) void k_scan(
    const int* __restrict__ deg, int* __restrict__ rowptr,
    int* __restrict__ cursor)
{
    __shared__ int sums[256];
    __shared__ int offs[257];
    const int t = threadIdx.x;
    const int CH = (BN + 255) / 256;         // 157
    int lo = t * CH;
    int hi = lo + CH; if (hi > BN) hi = BN;
    int s = 0;
    for (int i = lo; i < hi; ++i) s += deg[i];
    sums[t] = s;
    __syncthreads();
    if (t == 0) {
        int acc = 0;
        for (int i = 0; i < 256; ++i) { offs[i] = acc; acc += sums[i]; }
        offs[256] = acc;
    }
    __syncthreads();
    int acc = offs[t];
    for (int i = lo; i < hi; ++i) {
        rowptr[i] = acc; cursor[i] = acc; acc += deg[i];
    }
    if (t == 0) rowptr[BN] = offs[256];
}

// ---------------------------------------------------------------------------
// Kernel C: per edge: ex[8] = mask ? exp(leaky_relu(s_src+s_trg)) : 0;
// den[trg] += ex (atomic); claim CSR slot, write esrc[pos], exs[pos][8].
// ---------------------------------------------------------------------------
__global__ __launch_bounds__(256) void k_edge(
    const int* __restrict__ ei, const float* __restrict__ mask,
    const float* __restrict__ ssrc, const float* __restrict__ strg,
    int* __restrict__ cursor, int* __restrict__ esrc,
    float* __restrict__ exs, float* __restrict__ den)
{
    int e = blockIdx.x * 256 + threadIdx.x;
    if (e >= BE) return;
    int b  = e / EE;
    int le = e - b * EE;
    int src = ei[b * 2 * EE + le]      + b * NN;
    int trg = ei[b * 2 * EE + EE + le] + b * NN;
    float m = mask[e];

    float4 s0 = ((const float4*)(ssrc + (size_t)src * HH))[0];
    float4 s1 = ((const float4*)(ssrc + (size_t)src * HH))[1];
    float4 t0 = ((const float4*)(strg + (size_t)trg * HH))[0];
    float4 t1 = ((const float4*)(strg + (size_t)trg * HH))[1];

    float sc[8] = { s0.x + t0.x, s0.y + t0.y, s0.z + t0.z, s0.w + t0.w,
                    s1.x + t1.x, s1.y + t1.y, s1.z + t1.z, s1.w + t1.w };

    int pos = atomicAdd(&cursor[trg], 1);
    esrc[pos] = src;

    float* exo = exs + (size_t)pos * HH;
    float* dn  = den + (size_t)trg * HH;
#pragma unroll
    for (int h = 0; h < 8; ++h) {
        float v = sc[h];
        v = v > 0.f ? v : 0.2f * v;            // leaky_relu(0.2)
        v = (m > 0.f) ? __expf(v) : 0.f;       // masked -> 0
        exo[h] = v;
        atomicAdd(dn + h, v);
    }
}

// ---------------------------------------------------------------------------
// Kernel D: one 64-lane wave per target node; gather+accumulate its edges,
// fuse bias + ELU, write out exactly once (no atomics, no out memset).
// ---------------------------------------------------------------------------
__global__ __launch_bounds__(256) void k_gather(
    const int* __restrict__ rowptr, const int* __restrict__ esrc,
    const float* __restrict__ exs, const float* __restrict__ den,
    const __hip_bfloat16* __restrict__ proj, const float* __restrict__ bias,
    float* __restrict__ out)
{
    int gid  = blockIdx.x * 256 + threadIdx.x;
    int node = gid >> 6;
    int lane = gid & 63;
    if (node >= BN) return;
    int h = lane >> 3;                         // head of columns lane*4..+3
    float inv = 1.f / (den[(size_t)node * HH + h] + 1e-16f);
    int lo = rowptr[node], hi = rowptr[node + 1];

    float acc0 = 0.f, acc1 = 0.f, acc2 = 0.f, acc3 = 0.f;
    for (int p = lo; p < hi; ++p) {
        int src = esrc[p];                      // wave-uniform -> broadcast
        float a = exs[(size_t)p * HH + h] * inv;
        ushort4 q = ((const ushort4*)(proj + (size_t)src * CC))[lane];
        acc0 += bf2f(q.x) * a;
        acc1 += bf2f(q.y) * a;
        acc2 += bf2f(q.z) * a;
        acc3 += bf2f(q.w) * a;
    }

    float4 bv = ((const float4*)bias)[lane];
    float o0 = acc0 + bv.x, o1 = acc1 + bv.y, o2 = acc2 + bv.z, o3 = acc3 + bv.w;
    o0 = o0 > 0.f ? o0 : __expf(o0) - 1.f;
    o1 = o1 > 0.f ? o1 : __expf(o1) - 1.f;
    o2 = o2 > 0.f ? o2 : __expf(o2) - 1.f;
    o3 = o3 > 0.f ? o3 : __expf(o3) - 1.f;
    ((float4*)(out + (size_t)node * CC))[lane] = make_float4(o0, o1, o2, o3);
}

// ---------------------------------------------------------------------------
extern "C" void kernel_launch(void* const* d_in, const int* in_sizes, int n_in,
                              void* d_out, int out_size, void* d_ws, size_t ws_size,
                              hipStream_t stream)
{
    const float* x     = (const float*)d_in[0];
    const int*   ei    = (const int*)  d_in[1];
    const float* mask  = (const float*)d_in[2];
    const float* Wm    = (const float*)d_in[3];
    const float* a_src = (const float*)d_in[4];
    const float* a_trg = (const float*)d_in[5];
    const float* bias  = (const float*)d_in[6];
    float* out = (float*)d_out;

    char* ws = (char*)d_ws;
    size_t off = 0;
    __hip_bfloat16* proj = (__hip_bfloat16*)(ws + off); off += (size_t)BN * CC * 2;   // 20.48 MB
    float* ssrc   = (float*)(ws + off); off += (size_t)BN * HH * 4;                   //  1.28 MB
    float* strg   = (float*)(ws + off); off += (size_t)BN * HH * 4;                   //  1.28 MB
    float* exs    = (float*)(ws + off); off += (size_t)BE * HH * 4;                   // 20.48 MB
    float* den    = (float*)(ws + off); off += (size_t)BN * HH * 4;                   //  1.28 MB
    int*   deg    = (int*)  (ws + off); off += (size_t)BN * 4;                        //  0.16 MB
    int*   rowptr = (int*)  (ws + off); off += ((size_t)(BN + 1) * 4 + 15) & ~15ull;  //  0.16 MB
    int*   cursor = (int*)  (ws + off); off += (size_t)BN * 4;                        //  0.16 MB
    int*   esrc   = (int*)  (ws + off); off += (size_t)BE * 4;                        //  2.56 MB

    hipMemsetAsync(deg, 0, (size_t)BN * 4, stream);
    hipMemsetAsync(den, 0, (size_t)BN * HH * 4, stream);

    k_proj <<<BN / 16, 256, 0, stream>>>(x, Wm, a_src, a_trg, proj, ssrc, strg);
    k_count<<<(BE + 255) / 256, 256, 0, stream>>>(ei, deg);
    k_scan <<<1, 256, 0, stream>>>(deg, rowptr, cursor);
    k_edge <<<(BE + 255) / 256, 256, 0, stream>>>(ei, mask, ssrc, strg,
                                                  cursor, esrc, exs, den);
    k_gather<<<(BN * 64) / 256, 256, 0, stream>>>(rowptr, esrc, exs, den,
                                                  proj, bias, out);
}

// Round 3
// 427.516 us; speedup vs baseline: 6.0700x; 1.5721x over previous
//
#include <hip/hip_runtime.h>
#include <hip/hip_bf16.h>

#define BB   4
#define NN   10000
#define EE   160000
#define FIN  256
#define HH   8
#define FO   32
#define CC   256            // H*FO
#define BN   40000          // B*N
#define BE   640000         // B*E

__device__ __forceinline__ float bf2f(unsigned short u) {
    unsigned int v = ((unsigned int)u) << 16;
    return __uint_as_float(v);
}

// ---------------------------------------------------------------------------
// Kernel A: proj = x @ W^T (f32), store proj as bf16, compute per-node
// s_src[h] = proj[n,h,:]·a_src[h], s_trg likewise (f32, shuffle reduce).
// ---------------------------------------------------------------------------
__global__ __launch_bounds__(256) void k_proj(
    const float* __restrict__ x, const float* __restrict__ Wm,
    const float* __restrict__ a_src, const float* __restrict__ a_trg,
    __hip_bfloat16* __restrict__ proj, float* __restrict__ ssrc,
    float* __restrict__ strg)
{
    __shared__ float xs[16 * FIN];
    const int t = threadIdx.x;
    const int row0 = blockIdx.x * 16;

    const float4* xg = (const float4*)(x + (size_t)row0 * FIN);
    float4* xsw = (float4*)xs;
#pragma unroll
    for (int i = 0; i < 4; ++i) xsw[i * 256 + t] = xg[i * 256 + t];
    __syncthreads();

    float acc[16];
#pragma unroll
    for (int r = 0; r < 16; ++r) acc[r] = 0.f;

    const float4* w4  = (const float4*)(Wm + (size_t)t * FIN);
    const float4* xs4 = (const float4*)xs;
    for (int k4 = 0; k4 < FIN / 4; ++k4) {
        float4 w = w4[k4];
#pragma unroll
        for (int r = 0; r < 16; ++r) {
            float4 xv = xs4[r * (FIN / 4) + k4];
            acc[r] += xv.x * w.x + xv.y * w.y + xv.z * w.z + xv.w * w.w;
        }
    }

    const float as = a_src[t];
    const float at = a_trg[t];
    const int  h  = t >> 5;
    const bool writer = (t & 31) == 0;
#pragma unroll
    for (int r = 0; r < 16; ++r) {
        proj[(size_t)(row0 + r) * CC + t] = __float2bfloat16(acc[r]);
        float vs = acc[r] * as;
        float vt = acc[r] * at;
#pragma unroll
        for (int off = 16; off >= 1; off >>= 1) {
            vs += __shfl_xor(vs, off);
            vt += __shfl_xor(vt, off);
        }
        if (writer) {
            ssrc[(row0 + r) * HH + h] = vs;
            strg[(row0 + r) * HH + h] = vt;
        }
    }
}

// ---------------------------------------------------------------------------
// Kernel B1: deg[trg]++ histogram
// ---------------------------------------------------------------------------
__global__ __launch_bounds__(256) void k_count(
    const int* __restrict__ ei, int* __restrict__ deg)
{
    int e = blockIdx.x * 256 + threadIdx.x;
    if (e >= BE) return;
    int b  = e / EE;
    int le = e - b * EE;
    int trg = ei[b * 2 * EE + EE + le] + b * NN;
    atomicAdd(&deg[trg], 1);
}

// ---------------------------------------------------------------------------
// Kernel B2: single-block exclusive scan over deg[BN] -> rowptr, cursor
// ---------------------------------------------------------------------------
__global__ __launch_bounds__(256) void k_scan(
    const int* __restrict__ deg, int* __restrict__ rowptr,
    int* __restrict__ cursor)
{
    __shared__ int sums[256];
    __shared__ int offs[257];
    const int t = threadIdx.x;
    const int CH = (BN + 255) / 256;         // 157
    int lo = t * CH;
    int hi = lo + CH; if (hi > BN) hi = BN;
    int s = 0;
    for (int i = lo; i < hi; ++i) s += deg[i];
    sums[t] = s;
    __syncthreads();
    if (t == 0) {
        int acc = 0;
        for (int i = 0; i < 256; ++i) { offs[i] = acc; acc += sums[i]; }
        offs[256] = acc;
    }
    __syncthreads();
    int acc = offs[t];
    for (int i = lo; i < hi; ++i) {
        rowptr[i] = acc; cursor[i] = acc; acc += deg[i];
    }
    if (t == 0) rowptr[BN] = offs[256];
}

// ---------------------------------------------------------------------------
// Kernel C: per edge: claim CSR slot for target, record src + mask bit.
// 4 bytes written per edge; the only atomic is the slot cursor.
// ---------------------------------------------------------------------------
__global__ __launch_bounds__(256) void k_edge(
    const int* __restrict__ ei, const float* __restrict__ mask,
    int* __restrict__ cursor, int* __restrict__ esrc)
{
    int e = blockIdx.x * 256 + threadIdx.x;
    if (e >= BE) return;
    int b  = e / EE;
    int le = e - b * EE;
    int src = ei[b * 2 * EE + le]      + b * NN;
    int trg = ei[b * 2 * EE + EE + le] + b * NN;
    int pos = atomicAdd(&cursor[trg], 1);
    esrc[pos] = src | (mask[e] > 0.f ? 0 : (int)0x80000000);
}

// ---------------------------------------------------------------------------
// Kernel D: one 64-lane wave per target node. Recompute edge scores on the
// fly (ssrc/strg are L2-resident), accumulate unnormalized ex*proj and den,
// normalize once, fuse bias + ELU, write out exactly once.
// ---------------------------------------------------------------------------
__global__ __launch_bounds__(256) void k_gather(
    const int* __restrict__ rowptr, const int* __restrict__ esrc,
    const float* __restrict__ ssrc, const float* __restrict__ strg,
    const __hip_bfloat16* __restrict__ proj, const float* __restrict__ bias,
    float* __restrict__ out)
{
    int gid  = blockIdx.x * 256 + threadIdx.x;
    int node = gid >> 6;
    int lane = gid & 63;
    if (node >= BN) return;
    int h = lane >> 3;                          // head of columns lane*4..+3
    float st = strg[(size_t)node * HH + h];     // 8 distinct dwords per wave
    int lo = rowptr[node], hi = rowptr[node + 1];

    float acc0 = 0.f, acc1 = 0.f, acc2 = 0.f, acc3 = 0.f, den = 0.f;
    for (int p = lo; p < hi; ++p) {
        int sv  = esrc[p];                      // wave-uniform -> scalar
        int src = sv & 0x7fffffff;
        float s = ssrc[(size_t)src * HH + h] + st;
        s = s > 0.f ? s : 0.2f * s;             // leaky_relu(0.2)
        float ex = (sv >= 0) ? __expf(s) : 0.f; // masked edge -> 0
        den += ex;
        ushort4 q = ((const ushort4*)(proj + (size_t)src * CC))[lane];
        acc0 += bf2f(q.x) * ex;
        acc1 += bf2f(q.y) * ex;
        acc2 += bf2f(q.z) * ex;
        acc3 += bf2f(q.w) * ex;
    }

    float inv = 1.f / (den + 1e-16f);
    float4 bv = ((const float4*)bias)[lane];
    float o0 = acc0 * inv + bv.x, o1 = acc1 * inv + bv.y;
    float o2 = acc2 * inv + bv.z, o3 = acc3 * inv + bv.w;
    o0 = o0 > 0.f ? o0 : __expf(o0) - 1.f;
    o1 = o1 > 0.f ? o1 : __expf(o1) - 1.f;
    o2 = o2 > 0.f ? o2 : __expf(o2) - 1.f;
    o3 = o3 > 0.f ? o3 : __expf(o3) - 1.f;
    ((float4*)(out + (size_t)node * CC))[lane] = make_float4(o0, o1, o2, o3);
}

// ---------------------------------------------------------------------------
extern "C" void kernel_launch(void* const* d_in, const int* in_sizes, int n_in,
                              void* d_out, int out_size, void* d_ws, size_t ws_size,
                              hipStream_t stream)
{
    const float* x     = (const float*)d_in[0];
    const int*   ei    = (const int*)  d_in[1];
    const float* mask  = (const float*)d_in[2];
    const float* Wm    = (const float*)d_in[3];
    const float* a_src = (const float*)d_in[4];
    const float* a_trg = (const float*)d_in[5];
    const float* bias  = (const float*)d_in[6];
    float* out = (float*)d_out;

    char* ws = (char*)d_ws;
    size_t off = 0;
    __hip_bfloat16* proj = (__hip_bfloat16*)(ws + off); off += (size_t)BN * CC * 2;   // 20.48 MB
    float* ssrc   = (float*)(ws + off); off += (size_t)BN * HH * 4;                   //  1.28 MB
    float* strg   = (float*)(ws + off); off += (size_t)BN * HH * 4;                   //  1.28 MB
    int*   deg    = (int*)  (ws + off); off += (size_t)BN * 4;                        //  0.16 MB
    int*   rowptr = (int*)  (ws + off); off += ((size_t)(BN + 1) * 4 + 15) & ~15ull;  //  0.16 MB
    int*   cursor = (int*)  (ws + off); off += (size_t)BN * 4;                        //  0.16 MB
    int*   esrc   = (int*)  (ws + off); off += (size_t)BE * 4;                        //  2.56 MB

    hipMemsetAsync(deg, 0, (size_t)BN * 4, stream);

    k_proj <<<BN / 16, 256, 0, stream>>>(x, Wm, a_src, a_trg, proj, ssrc, strg);
    k_count<<<(BE + 255) / 256, 256, 0, stream>>>(ei, deg);
    k_scan <<<1, 256, 0, stream>>>(deg, rowptr, cursor);
    k_edge <<<(BE + 255) / 256, 256, 0, stream>>>(ei, mask, cursor, esrc);
    k_gather<<<(BN * 64) / 256, 256, 0, stream>>>(rowptr, esrc, ssrc, strg,
                                                  proj, bias, out);
}

// Round 4
// 289.704 us; speedup vs baseline: 8.9576x; 1.4757x over previous
//
#include <hip/hip_runtime.h>
#include <hip/hip_bf16.h>

#define BB   4
#define NN   10000
#define EE   160000
#define FIN  256
#define HH   8
#define FO   32
#define CC   256            // H*FO
#define BN   40000          // B*N
#define BE   640000         // B*E

typedef unsigned short ushort_t;
typedef __attribute__((ext_vector_type(8))) __bf16 bf16x8;
typedef __attribute__((ext_vector_type(4))) float  f32x4;

__device__ __forceinline__ float bf2f(unsigned short u) {
    unsigned int v = ((unsigned int)u) << 16;
    return __uint_as_float(v);
}
__device__ __forceinline__ unsigned short f2bf(float f) {
    unsigned int u = __float_as_uint(f);
    u += 0x7fffu + ((u >> 16) & 1u);   // round-to-nearest-even
    return (unsigned short)(u >> 16);
}

// ---------------------------------------------------------------------------
// Kernel 0: f32 -> bf16 bulk convert (8 elems/thread, 32B in / 16B out)
// ---------------------------------------------------------------------------
__global__ __launch_bounds__(256) void k_cvt(
    const float* __restrict__ src, unsigned short* __restrict__ dst, int n8)
{
    int i = blockIdx.x * 256 + threadIdx.x;
    if (i >= n8) return;
    const float4* s = (const float4*)src + (size_t)i * 2;
    float4 v0 = s[0], v1 = s[1];
    float f[8] = {v0.x, v0.y, v0.z, v0.w, v1.x, v1.y, v1.z, v1.w};
    union { unsigned short u[8]; uint4 q; } o;
#pragma unroll
    for (int j = 0; j < 8; ++j) o.u[j] = f2bf(f[j]);
    ((uint4*)dst)[i] = o.q;
}

// ---------------------------------------------------------------------------
// Kernel 1: proj = xb @ Wb^T via MFMA bf16. M=40000, N=256, K=256.
// 128x128 tile, BK=64, 4 waves (2x2), global_load_lds staging with
// XOR-swizzled layout (inverse-swizzle on the global source, swizzle on read).
// ---------------------------------------------------------------------------
__global__ __launch_bounds__(256) void k_gemm(
    const unsigned short* __restrict__ xb, const unsigned short* __restrict__ wb,
    unsigned short* __restrict__ proj)
{
    __shared__ alignas(16) unsigned short As[128 * 64];
    __shared__ alignas(16) unsigned short Bs[128 * 64];

    const int t    = threadIdx.x;
    const int lane = t & 63;
    const int wid  = t >> 6;
    const int wr   = wid >> 1, wc = wid & 1;
    const int bm   = blockIdx.x >> 1;
    const int bn   = blockIdx.x & 1;
    const int row0 = bm * 128, col0 = bn * 128;

    // staging map: pass p, thread t fills LDS elems [p*2048 + t*8, +8)
    const int srow = t >> 3;            // tile row (within 32-row pass group)
    const int scol = (t & 7) * 8;

    f32x4 acc[4][4] = {};

    for (int kt = 0; kt < 4; ++kt) {
        const int k0 = kt * 64;
#pragma unroll
        for (int p = 0; p < 4; ++p) {
            int tr = p * 32 + srow;                       // tile row 0..127
            int cg = scol ^ ((tr & 7) << 3);              // inverse-swizzled col
            int gra = row0 + tr; if (gra > BN - 1) gra = BN - 1;  // M-tail clamp
            const unsigned short* ga = xb + (size_t)gra * FIN + k0 + cg;
            const unsigned short* gb = wb + (size_t)(col0 + tr) * FIN + k0 + cg;
            __builtin_amdgcn_global_load_lds(
                (const __attribute__((address_space(1))) void*)ga,
                (__attribute__((address_space(3))) void*)&As[p * 2048 + t * 8],
                16, 0, 0);
            __builtin_amdgcn_global_load_lds(
                (const __attribute__((address_space(1))) void*)gb,
                (__attribute__((address_space(3))) void*)&Bs[p * 2048 + t * 8],
                16, 0, 0);
        }
        __syncthreads();   // drains vmcnt before any wave reads LDS

#pragma unroll
        for (int kk = 0; kk < 2; ++kk) {
            bf16x8 af[4], bfr[4];
#pragma unroll
            for (int m = 0; m < 4; ++m) {
                int row = wr * 64 + m * 16 + (lane & 15);
                int col = (kk * 32 + (lane >> 4) * 8) ^ ((row & 7) << 3);
                af[m] = *(const bf16x8*)&As[row * 64 + col];
            }
#pragma unroll
            for (int n = 0; n < 4; ++n) {
                int row = wc * 64 + n * 16 + (lane & 15);
                int col = (kk * 32 + (lane >> 4) * 8) ^ ((row & 7) << 3);
                bfr[n] = *(const bf16x8*)&Bs[row * 64 + col];
            }
#pragma unroll
            for (int m = 0; m < 4; ++m)
#pragma unroll
                for (int n = 0; n < 4; ++n)
                    acc[m][n] = __builtin_amdgcn_mfma_f32_16x16x32_bf16(
                        af[m], bfr[n], acc[m][n], 0, 0, 0);
        }
        __syncthreads();
    }

    // epilogue: D row=(lane>>4)*4+j, col=lane&15 (verified m89/m91 mapping)
    const int rbase = row0 + wr * 64 + (lane >> 4) * 4;
    const int cbase = col0 + wc * 64 + (lane & 15);
#pragma unroll
    for (int m = 0; m < 4; ++m)
#pragma unroll
        for (int n = 0; n < 4; ++n)
#pragma unroll
            for (int j = 0; j < 4; ++j) {
                int r = rbase + m * 16 + j;
                int c = cbase + n * 16;
                if (r < BN) proj[(size_t)r * CC + c] = f2bf(acc[m][n][j]);
            }
}

// ---------------------------------------------------------------------------
// Kernel 2: per-node attention scores. Thread t: node = blk*32 + t>>3,
// head = t&7; reads proj[node][h*32..+32] (64B contiguous), full dot -> no
// cross-lane reduction.
// ---------------------------------------------------------------------------
__global__ __launch_bounds__(256) void k_score(
    const unsigned short* __restrict__ proj,
    const float* __restrict__ a_src, const float* __restrict__ a_trg,
    float* __restrict__ ssrc, float* __restrict__ strg)
{
    __shared__ float sa[CC], sb[CC];
    int t = threadIdx.x;
    sa[t] = a_src[t];
    sb[t] = a_trg[t];
    __syncthreads();
    int node = blockIdx.x * 32 + (t >> 3);
    int h    = t & 7;
    const uint4* q4 = (const uint4*)(proj + (size_t)node * CC + h * 32);
    const float* pa = sa + h * 32;
    const float* pb = sb + h * 32;
    float vs = 0.f, vt = 0.f;
#pragma unroll
    for (int i = 0; i < 4; ++i) {
        uint4 q = q4[i];
        unsigned int v[4] = {q.x, q.y, q.z, q.w};
#pragma unroll
        for (int j = 0; j < 4; ++j) {
            float lo = __uint_as_float(v[j] << 16);
            float hi = __uint_as_float(v[j] & 0xffff0000u);
            int c = i * 8 + j * 2;
            vs += lo * pa[c] + hi * pa[c + 1];
            vt += lo * pb[c] + hi * pb[c + 1];
        }
    }
    ssrc[(size_t)node * HH + h] = vs;
    strg[(size_t)node * HH + h] = vt;
}

// ---------------------------------------------------------------------------
// Kernel B1: deg[trg]++ histogram
// ---------------------------------------------------------------------------
__global__ __launch_bounds__(256) void k_count(
    const int* __restrict__ ei, int* __restrict__ deg)
{
    int e = blockIdx.x * 256 + threadIdx.x;
    if (e >= BE) return;
    int b  = e / EE;
    int le = e - b * EE;
    int trg = ei[b * 2 * EE + EE + le] + b * NN;
    atomicAdd(&deg[trg], 1);
}

// ---------------------------------------------------------------------------
// Kernel B2: single-block exclusive scan over deg[BN] -> rowptr, cursor
// ---------------------------------------------------------------------------
__global__ __launch_bounds__(256) void k_scan(
    const int* __restrict__ deg, int* __restrict__ rowptr,
    int* __restrict__ cursor)
{
    __shared__ int sums[256];
    __shared__ int offs[257];
    const int t = threadIdx.x;
    const int CH = (BN + 255) / 256;         // 157
    int lo = t * CH;
    int hi = lo + CH; if (hi > BN) hi = BN;
    int s = 0;
    for (int i = lo; i < hi; ++i) s += deg[i];
    sums[t] = s;
    __syncthreads();
    if (t == 0) {
        int acc = 0;
        for (int i = 0; i < 256; ++i) { offs[i] = acc; acc += sums[i]; }
        offs[256] = acc;
    }
    __syncthreads();
    int acc = offs[t];
    for (int i = lo; i < hi; ++i) {
        rowptr[i] = acc; cursor[i] = acc; acc += deg[i];
    }
    if (t == 0) rowptr[BN] = offs[256];
}

// ---------------------------------------------------------------------------
// Kernel C: per edge: claim CSR slot for target, record src + mask bit.
// ---------------------------------------------------------------------------
__global__ __launch_bounds__(256) void k_edge(
    const int* __restrict__ ei, const float* __restrict__ mask,
    int* __restrict__ cursor, int* __restrict__ esrc)
{
    int e = blockIdx.x * 256 + threadIdx.x;
    if (e >= BE) return;
    int b  = e / EE;
    int le = e - b * EE;
    int src = ei[b * 2 * EE + le]      + b * NN;
    int trg = ei[b * 2 * EE + EE + le] + b * NN;
    int pos = atomicAdd(&cursor[trg], 1);
    esrc[pos] = src | (mask[e] > 0.f ? 0 : (int)0x80000000);
}

// ---------------------------------------------------------------------------
// Kernel D: one 64-lane wave per target node; recompute scores on the fly,
// accumulate unnormalized ex*proj and den, normalize, bias+ELU, store once.
// ---------------------------------------------------------------------------
__global__ __launch_bounds__(256) void k_gather(
    const int* __restrict__ rowptr, const int* __restrict__ esrc,
    const float* __restrict__ ssrc, const float* __restrict__ strg,
    const unsigned short* __restrict__ proj, const float* __restrict__ bias,
    float* __restrict__ out)
{
    int gid  = blockIdx.x * 256 + threadIdx.x;
    int node = gid >> 6;
    int lane = gid & 63;
    if (node >= BN) return;
    int h = lane >> 3;                          // head of columns lane*4..+3
    float st = strg[(size_t)node * HH + h];
    int lo = rowptr[node], hi = rowptr[node + 1];

    float acc0 = 0.f, acc1 = 0.f, acc2 = 0.f, acc3 = 0.f, den = 0.f;
    for (int p = lo; p < hi; ++p) {
        int sv  = esrc[p];                      // wave-uniform -> scalar
        int src = sv & 0x7fffffff;
        float s = ssrc[(size_t)src * HH + h] + st;
        s = s > 0.f ? s : 0.2f * s;             // leaky_relu(0.2)
        float ex = (sv >= 0) ? __expf(s) : 0.f; // masked edge -> 0
        den += ex;
        ushort4 q = ((const ushort4*)(proj + (size_t)src * CC))[lane];
        acc0 += bf2f(q.x) * ex;
        acc1 += bf2f(q.y) * ex;
        acc2 += bf2f(q.z) * ex;
        acc3 += bf2f(q.w) * ex;
    }

    float inv = 1.f / (den + 1e-16f);
    float4 bv = ((const float4*)bias)[lane];
    float o0 = acc0 * inv + bv.x, o1 = acc1 * inv + bv.y;
    float o2 = acc2 * inv + bv.z, o3 = acc3 * inv + bv.w;
    o0 = o0 > 0.f ? o0 : __expf(o0) - 1.f;
    o1 = o1 > 0.f ? o1 : __expf(o1) - 1.f;
    o2 = o2 > 0.f ? o2 : __expf(o2) - 1.f;
    o3 = o3 > 0.f ? o3 : __expf(o3) - 1.f;
    ((float4*)(out + (size_t)node * CC))[lane] = make_float4(o0, o1, o2, o3);
}

// ---------------------------------------------------------------------------
extern "C" void kernel_launch(void* const* d_in, const int* in_sizes, int n_in,
                              void* d_out, int out_size, void* d_ws, size_t ws_size,
                              hipStream_t stream)
{
    const float* x     = (const float*)d_in[0];
    const int*   ei    = (const int*)  d_in[1];
    const float* mask  = (const float*)d_in[2];
    const float* Wm    = (const float*)d_in[3];
    const float* a_src = (const float*)d_in[4];
    const float* a_trg = (const float*)d_in[5];
    const float* bias  = (const float*)d_in[6];
    float* out = (float*)d_out;

    char* ws = (char*)d_ws;
    size_t off = 0;
    unsigned short* xb = (unsigned short*)(ws + off); off += (size_t)BN * FIN * 2; // 20.48 MB
    unsigned short* wb = (unsigned short*)(ws + off); off += (size_t)CC * FIN * 2; //  0.13 MB
    unsigned short* proj = (unsigned short*)(ws + off); off += (size_t)BN * CC * 2;// 20.48 MB
    float* ssrc = (float*)(ws + off); off += (size_t)BN * HH * 4;                  //  1.28 MB
    float* strg = (float*)(ws + off); off += (size_t)BN * HH * 4;                  //  1.28 MB

    // CSR scratch aliases the xb region (xb is dead after k_gemm; the memset
    // below is stream-ordered after k_gemm, so no overlap hazard).
    char* ws2 = (char*)xb;
    int* deg    = (int*)ws2;
    int* rowptr = (int*)(ws2 + (size_t)BN * 4);
    int* cursor = (int*)(ws2 + (size_t)BN * 4 + (size_t)(BN + 4) * 4);
    int* esrc   = (int*)(ws2 + (size_t)BN * 4 + (size_t)(BN + 4) * 4 + (size_t)BN * 4);

    k_cvt  <<<(BN * FIN / 8 + 255) / 256, 256, 0, stream>>>(x,  xb, BN * FIN / 8);
    k_cvt  <<<(CC * FIN / 8 + 255) / 256, 256, 0, stream>>>(Wm, wb, CC * FIN / 8);
    k_gemm <<<((BN + 127) / 128) * 2, 256, 0, stream>>>(xb, wb, proj);
    k_score<<<BN / 32, 256, 0, stream>>>(proj, a_src, a_trg, ssrc, strg);

    hipMemsetAsync(deg, 0, (size_t)BN * 4, stream);   // after k_gemm in stream order
    k_count<<<(BE + 255) / 256, 256, 0, stream>>>(ei, deg);
    k_scan <<<1, 256, 0, stream>>>(deg, rowptr, cursor);
    k_edge <<<(BE + 255) / 256, 256, 0, stream>>>(ei, mask, cursor, esrc);
    k_gather<<<(BN * 64) / 256, 256, 0, stream>>>(rowptr, esrc, ssrc, strg,
                                                  proj, bias, out);
}

// Round 5
// 152.827 us; speedup vs baseline: 16.9802x; 1.8956x over previous
//
#include <hip/hip_runtime.h>
#include <hip/hip_bf16.h>

#define BB   4
#define NN   10000
#define EE   160000
#define FIN  256
#define HH   8
#define FO   32
#define CC   256            // H*FO
#define BN   40000          // B*N
#define BE   640000         // B*E
#define NB   157            // ceil(BN/256)

typedef __attribute__((ext_vector_type(8))) __bf16 bf16x8;
typedef __attribute__((ext_vector_type(4))) float  f32x4;

__device__ __forceinline__ float bf2f(unsigned short u) {
    unsigned int v = ((unsigned int)u) << 16;
    return __uint_as_float(v);
}
__device__ __forceinline__ unsigned short f2bf(float f) {
    unsigned int u = __float_as_uint(f);
    u += 0x7fffu + ((u >> 16) & 1u);   // round-to-nearest-even
    return (unsigned short)(u >> 16);
}

// 256-thread block exclusive scan (int). lds4 is a __shared__ int[4].
__device__ __forceinline__ int block_excl_scan_256(int v, int t, int* lds4,
                                                   int* total)
{
    int lane = t & 63, wid = t >> 6;
    int incl = v;
#pragma unroll
    for (int off = 1; off < 64; off <<= 1) {
        int u = __shfl_up(incl, off);
        if (lane >= off) incl += u;
    }
    if (lane == 63) lds4[wid] = incl;
    __syncthreads();
    int w0 = lds4[0], w1 = lds4[1], w2 = lds4[2], w3 = lds4[3];
    int woff = (wid > 0 ? w0 : 0) + (wid > 1 ? w1 : 0) + (wid > 2 ? w2 : 0);
    *total = w0 + w1 + w2 + w3;
    return woff + incl - v;
}

// ---------------------------------------------------------------------------
// Kernel 0: f32 -> bf16 bulk convert
// ---------------------------------------------------------------------------
__global__ __launch_bounds__(256) void k_cvt(
    const float* __restrict__ src, unsigned short* __restrict__ dst, int n8)
{
    int i = blockIdx.x * 256 + threadIdx.x;
    if (i >= n8) return;
    const float4* s = (const float4*)src + (size_t)i * 2;
    float4 v0 = s[0], v1 = s[1];
    float f[8] = {v0.x, v0.y, v0.z, v0.w, v1.x, v1.y, v1.z, v1.w};
    union { unsigned short u[8]; uint4 q; } o;
#pragma unroll
    for (int j = 0; j < 8; ++j) o.u[j] = f2bf(f[j]);
    ((uint4*)dst)[i] = o.q;
}

// ---------------------------------------------------------------------------
// Kernel 1: proj = xb @ Wb^T via MFMA bf16 (128x128 tile, BK=64, 4 waves)
// ---------------------------------------------------------------------------
__global__ __launch_bounds__(256) void k_gemm(
    const unsigned short* __restrict__ xb, const unsigned short* __restrict__ wb,
    unsigned short* __restrict__ proj)
{
    __shared__ alignas(16) unsigned short As[128 * 64];
    __shared__ alignas(16) unsigned short Bs[128 * 64];

    const int t    = threadIdx.x;
    const int lane = t & 63;
    const int wid  = t >> 6;
    const int wr   = wid >> 1, wc = wid & 1;
    const int bm   = blockIdx.x >> 1;
    const int bn   = blockIdx.x & 1;
    const int row0 = bm * 128, col0 = bn * 128;

    const int srow = t >> 3;
    const int scol = (t & 7) * 8;

    f32x4 acc[4][4] = {};

    for (int kt = 0; kt < 4; ++kt) {
        const int k0 = kt * 64;
#pragma unroll
        for (int p = 0; p < 4; ++p) {
            int tr = p * 32 + srow;
            int cg = scol ^ ((tr & 7) << 3);
            int gra = row0 + tr; if (gra > BN - 1) gra = BN - 1;
            const unsigned short* ga = xb + (size_t)gra * FIN + k0 + cg;
            const unsigned short* gb = wb + (size_t)(col0 + tr) * FIN + k0 + cg;
            __builtin_amdgcn_global_load_lds(
                (const __attribute__((address_space(1))) void*)ga,
                (__attribute__((address_space(3))) void*)&As[p * 2048 + t * 8],
                16, 0, 0);
            __builtin_amdgcn_global_load_lds(
                (const __attribute__((address_space(1))) void*)gb,
                (__attribute__((address_space(3))) void*)&Bs[p * 2048 + t * 8],
                16, 0, 0);
        }
        __syncthreads();

#pragma unroll
        for (int kk = 0; kk < 2; ++kk) {
            bf16x8 af[4], bfr[4];
#pragma unroll
            for (int m = 0; m < 4; ++m) {
                int row = wr * 64 + m * 16 + (lane & 15);
                int col = (kk * 32 + (lane >> 4) * 8) ^ ((row & 7) << 3);
                af[m] = *(const bf16x8*)&As[row * 64 + col];
            }
#pragma unroll
            for (int n = 0; n < 4; ++n) {
                int row = wc * 64 + n * 16 + (lane & 15);
                int col = (kk * 32 + (lane >> 4) * 8) ^ ((row & 7) << 3);
                bfr[n] = *(const bf16x8*)&Bs[row * 64 + col];
            }
#pragma unroll
            for (int m = 0; m < 4; ++m)
#pragma unroll
                for (int n = 0; n < 4; ++n)
                    acc[m][n] = __builtin_amdgcn_mfma_f32_16x16x32_bf16(
                        af[m], bfr[n], acc[m][n], 0, 0, 0);
        }
        __syncthreads();
    }

    const int rbase = row0 + wr * 64 + (lane >> 4) * 4;
    const int cbase = col0 + wc * 64 + (lane & 15);
#pragma unroll
    for (int m = 0; m < 4; ++m)
#pragma unroll
        for (int n = 0; n < 4; ++n)
#pragma unroll
            for (int j = 0; j < 4; ++j) {
                int r = rbase + m * 16 + j;
                int c = cbase + n * 16;
                if (r < BN) proj[(size_t)r * CC + c] = f2bf(acc[m][n][j]);
            }
}

// ---------------------------------------------------------------------------
// Kernel 2: per-node attention scores (node = blk*32 + t>>3, head = t&7)
// ---------------------------------------------------------------------------
__global__ __launch_bounds__(256) void k_score(
    const unsigned short* __restrict__ proj,
    const float* __restrict__ a_src, const float* __restrict__ a_trg,
    float* __restrict__ ssrc, float* __restrict__ strg)
{
    __shared__ float sa[CC], sb[CC];
    int t = threadIdx.x;
    sa[t] = a_src[t];
    sb[t] = a_trg[t];
    __syncthreads();
    int node = blockIdx.x * 32 + (t >> 3);
    int h    = t & 7;
    const uint4* q4 = (const uint4*)(proj + (size_t)node * CC + h * 32);
    const float* pa = sa + h * 32;
    const float* pb = sb + h * 32;
    float vs = 0.f, vt = 0.f;
#pragma unroll
    for (int i = 0; i < 4; ++i) {
        uint4 q = q4[i];
        unsigned int v[4] = {q.x, q.y, q.z, q.w};
#pragma unroll
        for (int j = 0; j < 4; ++j) {
            float lo = __uint_as_float(v[j] << 16);
            float hi = __uint_as_float(v[j] & 0xffff0000u);
            int c = i * 8 + j * 2;
            vs += lo * pa[c] + hi * pa[c + 1];
            vt += lo * pb[c] + hi * pb[c + 1];
        }
    }
    ssrc[(size_t)node * HH + h] = vs;
    strg[(size_t)node * HH + h] = vt;
}

// ---------------------------------------------------------------------------
// Kernel B1: deg[trg]++ histogram, 4 edges/thread (int4)
// ---------------------------------------------------------------------------
__global__ __launch_bounds__(256) void k_count(
    const int* __restrict__ ei, int* __restrict__ deg)
{
    int i = blockIdx.x * 256 + threadIdx.x;      // i indexes groups of 4 edges
    if (i >= BE / 4) return;
    int e0 = i * 4;
    int b  = e0 / EE;                            // EE%4==0 -> same batch for all 4
    int le = e0 - b * EE;
    int4 tq = *(const int4*)(ei + (size_t)b * 2 * EE + EE + le);
    int base = b * NN;
    atomicAdd(&deg[tq.x + base], 1);
    atomicAdd(&deg[tq.y + base], 1);
    atomicAdd(&deg[tq.z + base], 1);
    atomicAdd(&deg[tq.w + base], 1);
}

// ---------------------------------------------------------------------------
// Scan pipeline: bsum (157 blocks) -> boff (1 block) -> fill (157 blocks)
// ---------------------------------------------------------------------------
__global__ __launch_bounds__(256) void k_bsum(
    const int* __restrict__ deg, int* __restrict__ bsum)
{
    __shared__ int w4[4];
    int t = threadIdx.x, i = blockIdx.x * 256 + t;
    int v = (i < BN) ? deg[i] : 0;
#pragma unroll
    for (int off = 32; off >= 1; off >>= 1) v += __shfl_xor(v, off);
    if ((t & 63) == 0) w4[t >> 6] = v;
    __syncthreads();
    if (t == 0) bsum[blockIdx.x] = w4[0] + w4[1] + w4[2] + w4[3];
}

__global__ __launch_bounds__(256) void k_boff(
    const int* __restrict__ bsum, int* __restrict__ boff,
    int* __restrict__ rowptr)
{
    __shared__ int w4[4];
    int t = threadIdx.x;
    int v = (t < NB) ? bsum[t] : 0;
    int total;
    int excl = block_excl_scan_256(v, t, w4, &total);
    if (t < NB) boff[t] = excl;
    if (t == 0) rowptr[BN] = total;
}

__global__ __launch_bounds__(256) void k_fill(
    const int* __restrict__ deg, const int* __restrict__ boff,
    int* __restrict__ rowptr, int* __restrict__ cursor)
{
    __shared__ int w4[4];
    int t = threadIdx.x, i = blockIdx.x * 256 + t;
    int v = (i < BN) ? deg[i] : 0;
    int total;
    int excl = block_excl_scan_256(v, t, w4, &total);
    if (i < BN) {
        int r = boff[blockIdx.x] + excl;
        rowptr[i] = r;
        cursor[i] = r;
    }
}

// ---------------------------------------------------------------------------
// Kernel C: per edge: claim CSR slot for target, record src + mask bit.
// ---------------------------------------------------------------------------
__global__ __launch_bounds__(256) void k_edge(
    const int* __restrict__ ei, const float* __restrict__ mask,
    int* __restrict__ cursor, int* __restrict__ esrc)
{
    int e = blockIdx.x * 256 + threadIdx.x;
    if (e >= BE) return;
    int b  = e / EE;
    int le = e - b * EE;
    int src = ei[b * 2 * EE + le]      + b * NN;
    int trg = ei[b * 2 * EE + EE + le] + b * NN;
    int pos = atomicAdd(&cursor[trg], 1);
    esrc[pos] = src | (mask[e] > 0.f ? 0 : (int)0x80000000);
}

// ---------------------------------------------------------------------------
// Kernel D: one wave per target node, 4-way unrolled edge loop for MLP.
// ---------------------------------------------------------------------------
__global__ __launch_bounds__(256) void k_gather(
    const int* __restrict__ rowptr, const int* __restrict__ esrc,
    const float* __restrict__ ssrc, const float* __restrict__ strg,
    const unsigned short* __restrict__ proj, const float* __restrict__ bias,
    float* __restrict__ out)
{
    int gid  = blockIdx.x * 256 + threadIdx.x;
    int node = gid >> 6;
    int lane = gid & 63;
    if (node >= BN) return;
    int h = lane >> 3;
    float st = strg[(size_t)node * HH + h];
    int lo = rowptr[node], hi = rowptr[node + 1];

    float acc0 = 0.f, acc1 = 0.f, acc2 = 0.f, acc3 = 0.f, den = 0.f;

    int p = lo;
    for (; p + 4 <= hi; p += 4) {
        // 4 independent chains: issue all loads up front
        int sv0 = esrc[p], sv1 = esrc[p + 1], sv2 = esrc[p + 2], sv3 = esrc[p + 3];
        int s0 = sv0 & 0x7fffffff, s1 = sv1 & 0x7fffffff;
        int s2 = sv2 & 0x7fffffff, s3 = sv3 & 0x7fffffff;
        float ss0 = ssrc[(size_t)s0 * HH + h];
        float ss1 = ssrc[(size_t)s1 * HH + h];
        float ss2 = ssrc[(size_t)s2 * HH + h];
        float ss3 = ssrc[(size_t)s3 * HH + h];
        ushort4 q0 = ((const ushort4*)(proj + (size_t)s0 * CC))[lane];
        ushort4 q1 = ((const ushort4*)(proj + (size_t)s1 * CC))[lane];
        ushort4 q2 = ((const ushort4*)(proj + (size_t)s2 * CC))[lane];
        ushort4 q3 = ((const ushort4*)(proj + (size_t)s3 * CC))[lane];

        float a0 = ss0 + st; a0 = a0 > 0.f ? a0 : 0.2f * a0;
        float a1 = ss1 + st; a1 = a1 > 0.f ? a1 : 0.2f * a1;
        float a2 = ss2 + st; a2 = a2 > 0.f ? a2 : 0.2f * a2;
        float a3 = ss3 + st; a3 = a3 > 0.f ? a3 : 0.2f * a3;
        float e0 = (sv0 >= 0) ? __expf(a0) : 0.f;
        float e1 = (sv1 >= 0) ? __expf(a1) : 0.f;
        float e2 = (sv2 >= 0) ? __expf(a2) : 0.f;
        float e3 = (sv3 >= 0) ? __expf(a3) : 0.f;
        den += (e0 + e1) + (e2 + e3);
        acc0 += bf2f(q0.x) * e0 + bf2f(q1.x) * e1 + bf2f(q2.x) * e2 + bf2f(q3.x) * e3;
        acc1 += bf2f(q0.y) * e0 + bf2f(q1.y) * e1 + bf2f(q2.y) * e2 + bf2f(q3.y) * e3;
        acc2 += bf2f(q0.z) * e0 + bf2f(q1.z) * e1 + bf2f(q2.z) * e2 + bf2f(q3.z) * e3;
        acc3 += bf2f(q0.w) * e0 + bf2f(q1.w) * e1 + bf2f(q2.w) * e2 + bf2f(q3.w) * e3;
    }
    for (; p < hi; ++p) {
        int sv  = esrc[p];
        int src = sv & 0x7fffffff;
        float s = ssrc[(size_t)src * HH + h] + st;
        s = s > 0.f ? s : 0.2f * s;
        float ex = (sv >= 0) ? __expf(s) : 0.f;
        den += ex;
        ushort4 q = ((const ushort4*)(proj + (size_t)src * CC))[lane];
        acc0 += bf2f(q.x) * ex;
        acc1 += bf2f(q.y) * ex;
        acc2 += bf2f(q.z) * ex;
        acc3 += bf2f(q.w) * ex;
    }

    float inv = 1.f / (den + 1e-16f);
    float4 bv = ((const float4*)bias)[lane];
    float o0 = acc0 * inv + bv.x, o1 = acc1 * inv + bv.y;
    float o2 = acc2 * inv + bv.z, o3 = acc3 * inv + bv.w;
    o0 = o0 > 0.f ? o0 : __expf(o0) - 1.f;
    o1 = o1 > 0.f ? o1 : __expf(o1) - 1.f;
    o2 = o2 > 0.f ? o2 : __expf(o2) - 1.f;
    o3 = o3 > 0.f ? o3 : __expf(o3) - 1.f;
    ((float4*)(out + (size_t)node * CC))[lane] = make_float4(o0, o1, o2, o3);
}

// ---------------------------------------------------------------------------
extern "C" void kernel_launch(void* const* d_in, const int* in_sizes, int n_in,
                              void* d_out, int out_size, void* d_ws, size_t ws_size,
                              hipStream_t stream)
{
    const float* x     = (const float*)d_in[0];
    const int*   ei    = (const int*)  d_in[1];
    const float* mask  = (const float*)d_in[2];
    const float* Wm    = (const float*)d_in[3];
    const float* a_src = (const float*)d_in[4];
    const float* a_trg = (const float*)d_in[5];
    const float* bias  = (const float*)d_in[6];
    float* out = (float*)d_out;

    char* ws = (char*)d_ws;
    size_t off = 0;
    unsigned short* xb = (unsigned short*)(ws + off); off += (size_t)BN * FIN * 2; // 20.48 MB
    unsigned short* wb = (unsigned short*)(ws + off); off += (size_t)CC * FIN * 2; //  0.13 MB
    unsigned short* proj = (unsigned short*)(ws + off); off += (size_t)BN * CC * 2;// 20.48 MB
    float* ssrc = (float*)(ws + off); off += (size_t)BN * HH * 4;                  //  1.28 MB
    float* strg = (float*)(ws + off); off += (size_t)BN * HH * 4;                  //  1.28 MB
    int*   bsum = (int*)  (ws + off); off += 256 * 4;
    int*   boff = (int*)  (ws + off); off += 256 * 4;

    // CSR scratch aliases xb (dead after k_gemm; stream order guarantees safety)
    char* ws2 = (char*)xb;
    int* deg    = (int*)ws2;
    int* rowptr = (int*)(ws2 + (size_t)BN * 4);
    int* cursor = (int*)(ws2 + (size_t)BN * 4 + (size_t)(BN + 4) * 4);
    int* esrc   = (int*)(ws2 + (size_t)BN * 4 + (size_t)(BN + 4) * 4 + (size_t)BN * 4);

    k_cvt  <<<(BN * FIN / 8 + 255) / 256, 256, 0, stream>>>(x,  xb, BN * FIN / 8);
    k_cvt  <<<(CC * FIN / 8 + 255) / 256, 256, 0, stream>>>(Wm, wb, CC * FIN / 8);
    k_gemm <<<((BN + 127) / 128) * 2, 256, 0, stream>>>(xb, wb, proj);
    k_score<<<BN / 32, 256, 0, stream>>>(proj, a_src, a_trg, ssrc, strg);

    hipMemsetAsync(deg, 0, (size_t)BN * 4, stream);   // stream-ordered after k_gemm
    k_count<<<(BE / 4 + 255) / 256, 256, 0, stream>>>(ei, deg);
    k_bsum <<<NB, 256, 0, stream>>>(deg, bsum);
    k_boff <<<1, 256, 0, stream>>>(bsum, boff, rowptr);
    k_fill <<<NB, 256, 0, stream>>>(deg, boff, rowptr, cursor);
    k_edge <<<(BE + 255) / 256, 256, 0, stream>>>(ei, mask, cursor, esrc);
    k_gather<<<(BN * 64) / 256, 256, 0, stream>>>(rowptr, esrc, ssrc, strg,
                                                  proj, bias, out);
}

// Round 6
// 150.965 us; speedup vs baseline: 17.1897x; 1.0123x over previous
//
#include <hip/hip_runtime.h>
#include <hip/hip_bf16.h>

#define BB   4
#define NN   10000
#define EE   160000
#define FIN  256
#define HH   8
#define FO   32
#define CC   256            // H*FO
#define BN   40000          // B*N
#define BE   640000         // B*E
#define NB   157            // ceil(BN/256)

#define XCVT 5000           // BN*FIN/8/256 blocks for x cvt
#define WCVT 32             // CC*FIN/8/256 blocks for W cvt
#define CNTB 625            // BE/4/256 blocks for histogram

typedef __attribute__((ext_vector_type(8))) __bf16 bf16x8;
typedef __attribute__((ext_vector_type(4))) float  f32x4;

__device__ __forceinline__ float bf2f(unsigned short u) {
    unsigned int v = ((unsigned int)u) << 16;
    return __uint_as_float(v);
}
__device__ __forceinline__ unsigned short f2bf(float f) {
    unsigned int u = __float_as_uint(f);
    u += 0x7fffu + ((u >> 16) & 1u);   // round-to-nearest-even
    return (unsigned short)(u >> 16);
}

__device__ __forceinline__ void cvt8(const float* __restrict__ src,
                                     unsigned short* __restrict__ dst, int i)
{
    const float4* s = (const float4*)src + (size_t)i * 2;
    float4 v0 = s[0], v1 = s[1];
    float f[8] = {v0.x, v0.y, v0.z, v0.w, v1.x, v1.y, v1.z, v1.w};
    union { unsigned short u[8]; uint4 q; } o;
#pragma unroll
    for (int j = 0; j < 8; ++j) o.u[j] = f2bf(f[j]);
    ((uint4*)dst)[i] = o.q;
}

// 256-thread block exclusive scan (int). lds4 is a __shared__ int[4].
__device__ __forceinline__ int block_excl_scan_256(int v, int t, int* lds4,
                                                   int* total)
{
    int lane = t & 63, wid = t >> 6;
    int incl = v;
#pragma unroll
    for (int off = 1; off < 64; off <<= 1) {
        int u = __shfl_up(incl, off);
        if (lane >= off) incl += u;
    }
    if (lane == 63) lds4[wid] = incl;
    __syncthreads();
    int w0 = lds4[0], w1 = lds4[1], w2 = lds4[2], w3 = lds4[3];
    int woff = (wid > 0 ? w0 : 0) + (wid > 1 ? w1 : 0) + (wid > 2 ? w2 : 0);
    *total = w0 + w1 + w2 + w3;
    return woff + incl - v;
}

// ---------------------------------------------------------------------------
// Kernel P: fused prep — cvt x->bf16, cvt W->bf16, deg histogram.
// Per-block uniform branch; grid = XCVT + WCVT + CNTB.
// ---------------------------------------------------------------------------
__global__ __launch_bounds__(256) void k_prep(
    const float* __restrict__ x, const float* __restrict__ Wm,
    const int* __restrict__ ei, unsigned short* __restrict__ xb,
    unsigned short* __restrict__ wb, int* __restrict__ deg)
{
    int blk = blockIdx.x, t = threadIdx.x;
    if (blk < XCVT) {
        cvt8(x, xb, blk * 256 + t);
    } else if (blk < XCVT + WCVT) {
        cvt8(Wm, wb, (blk - XCVT) * 256 + t);
    } else {
        int i = (blk - XCVT - WCVT) * 256 + t;      // 4 edges per thread
        int e0 = i * 4;
        int b  = e0 / EE;
        int le = e0 - b * EE;
        int4 tq = *(const int4*)(ei + (size_t)b * 2 * EE + EE + le);
        int base = b * NN;
        atomicAdd(&deg[tq.x + base], 1);
        atomicAdd(&deg[tq.y + base], 1);
        atomicAdd(&deg[tq.z + base], 1);
        atomicAdd(&deg[tq.w + base], 1);
    }
}

// ---------------------------------------------------------------------------
// Kernel 1: proj = xb @ Wb^T via MFMA bf16 (128x128 tile, BK=64, 4 waves)
// ---------------------------------------------------------------------------
__global__ __launch_bounds__(256) void k_gemm(
    const unsigned short* __restrict__ xb, const unsigned short* __restrict__ wb,
    unsigned short* __restrict__ proj)
{
    __shared__ alignas(16) unsigned short As[128 * 64];
    __shared__ alignas(16) unsigned short Bs[128 * 64];

    const int t    = threadIdx.x;
    const int lane = t & 63;
    const int wid  = t >> 6;
    const int wr   = wid >> 1, wc = wid & 1;
    const int bm   = blockIdx.x >> 1;
    const int bn   = blockIdx.x & 1;
    const int row0 = bm * 128, col0 = bn * 128;

    const int srow = t >> 3;
    const int scol = (t & 7) * 8;

    f32x4 acc[4][4] = {};

    for (int kt = 0; kt < 4; ++kt) {
        const int k0 = kt * 64;
#pragma unroll
        for (int p = 0; p < 4; ++p) {
            int tr = p * 32 + srow;
            int cg = scol ^ ((tr & 7) << 3);
            int gra = row0 + tr; if (gra > BN - 1) gra = BN - 1;
            const unsigned short* ga = xb + (size_t)gra * FIN + k0 + cg;
            const unsigned short* gb = wb + (size_t)(col0 + tr) * FIN + k0 + cg;
            __builtin_amdgcn_global_load_lds(
                (const __attribute__((address_space(1))) void*)ga,
                (__attribute__((address_space(3))) void*)&As[p * 2048 + t * 8],
                16, 0, 0);
            __builtin_amdgcn_global_load_lds(
                (const __attribute__((address_space(1))) void*)gb,
                (__attribute__((address_space(3))) void*)&Bs[p * 2048 + t * 8],
                16, 0, 0);
        }
        __syncthreads();

#pragma unroll
        for (int kk = 0; kk < 2; ++kk) {
            bf16x8 af[4], bfr[4];
#pragma unroll
            for (int m = 0; m < 4; ++m) {
                int row = wr * 64 + m * 16 + (lane & 15);
                int col = (kk * 32 + (lane >> 4) * 8) ^ ((row & 7) << 3);
                af[m] = *(const bf16x8*)&As[row * 64 + col];
            }
#pragma unroll
            for (int n = 0; n < 4; ++n) {
                int row = wc * 64 + n * 16 + (lane & 15);
                int col = (kk * 32 + (lane >> 4) * 8) ^ ((row & 7) << 3);
                bfr[n] = *(const bf16x8*)&Bs[row * 64 + col];
            }
#pragma unroll
            for (int m = 0; m < 4; ++m)
#pragma unroll
                for (int n = 0; n < 4; ++n)
                    acc[m][n] = __builtin_amdgcn_mfma_f32_16x16x32_bf16(
                        af[m], bfr[n], acc[m][n], 0, 0, 0);
        }
        __syncthreads();
    }

    const int rbase = row0 + wr * 64 + (lane >> 4) * 4;
    const int cbase = col0 + wc * 64 + (lane & 15);
#pragma unroll
    for (int m = 0; m < 4; ++m)
#pragma unroll
        for (int n = 0; n < 4; ++n)
#pragma unroll
            for (int j = 0; j < 4; ++j) {
                int r = rbase + m * 16 + j;
                int c = cbase + n * 16;
                if (r < BN) proj[(size_t)r * CC + c] = f2bf(acc[m][n][j]);
            }
}

// ---------------------------------------------------------------------------
// Kernel 2: per-node attention scores (node = blk*32 + t>>3, head = t&7)
// ---------------------------------------------------------------------------
__global__ __launch_bounds__(256) void k_score(
    const unsigned short* __restrict__ proj,
    const float* __restrict__ a_src, const float* __restrict__ a_trg,
    float* __restrict__ ssrc, float* __restrict__ strg)
{
    __shared__ float sa[CC], sb[CC];
    int t = threadIdx.x;
    sa[t] = a_src[t];
    sb[t] = a_trg[t];
    __syncthreads();
    int node = blockIdx.x * 32 + (t >> 3);
    int h    = t & 7;
    const uint4* q4 = (const uint4*)(proj + (size_t)node * CC + h * 32);
    const float* pa = sa + h * 32;
    const float* pb = sb + h * 32;
    float vs = 0.f, vt = 0.f;
#pragma unroll
    for (int i = 0; i < 4; ++i) {
        uint4 q = q4[i];
        unsigned int v[4] = {q.x, q.y, q.z, q.w};
#pragma unroll
        for (int j = 0; j < 4; ++j) {
            float lo = __uint_as_float(v[j] << 16);
            float hi = __uint_as_float(v[j] & 0xffff0000u);
            int c = i * 8 + j * 2;
            vs += lo * pa[c] + hi * pa[c + 1];
            vt += lo * pb[c] + hi * pb[c + 1];
        }
    }
    ssrc[(size_t)node * HH + h] = vs;
    strg[(size_t)node * HH + h] = vt;
}

// ---------------------------------------------------------------------------
// Scan pipeline: bsum (157 blocks) -> boff (1 block) -> fill (157 blocks)
// cursor[i] = CSR start of node i; after k_edge, cursor[i] = CSR end.
// ---------------------------------------------------------------------------
__global__ __launch_bounds__(256) void k_bsum(
    const int* __restrict__ deg, int* __restrict__ bsum)
{
    __shared__ int w4[4];
    int t = threadIdx.x, i = blockIdx.x * 256 + t;
    int v = (i < BN) ? deg[i] : 0;
#pragma unroll
    for (int off = 32; off >= 1; off >>= 1) v += __shfl_xor(v, off);
    if ((t & 63) == 0) w4[t >> 6] = v;
    __syncthreads();
    if (t == 0) bsum[blockIdx.x] = w4[0] + w4[1] + w4[2] + w4[3];
}

__global__ __launch_bounds__(256) void k_boff(
    const int* __restrict__ bsum, int* __restrict__ boff)
{
    __shared__ int w4[4];
    int t = threadIdx.x;
    int v = (t < NB) ? bsum[t] : 0;
    int total;
    int excl = block_excl_scan_256(v, t, w4, &total);
    if (t < NB) boff[t] = excl;
}

__global__ __launch_bounds__(256) void k_fill(
    const int* __restrict__ deg, const int* __restrict__ boff,
    int* __restrict__ cursor)
{
    __shared__ int w4[4];
    int t = threadIdx.x, i = blockIdx.x * 256 + t;
    int v = (i < BN) ? deg[i] : 0;
    int total;
    int excl = block_excl_scan_256(v, t, w4, &total);
    if (i < BN) cursor[i] = boff[blockIdx.x] + excl;
}

// ---------------------------------------------------------------------------
// Kernel C: per edge: claim CSR slot, write src index and the 8 per-head
// attention numerators ex = exp(leaky(s_src+s_trg)) (bf16, masked -> 0).
// ---------------------------------------------------------------------------
__global__ __launch_bounds__(256) void k_edge(
    const int* __restrict__ ei, const float* __restrict__ mask,
    const float* __restrict__ ssrc, const float* __restrict__ strg,
    int* __restrict__ cursor, int* __restrict__ esrc,
    unsigned short* __restrict__ exb)
{
    int e = blockIdx.x * 256 + threadIdx.x;
    if (e >= BE) return;
    int b  = e / EE;
    int le = e - b * EE;
    int src = ei[b * 2 * EE + le]      + b * NN;
    int trg = ei[b * 2 * EE + EE + le] + b * NN;
    float m = mask[e];

    int pos = atomicAdd(&cursor[trg], 1);
    esrc[pos] = src;

    float4 s0 = ((const float4*)(ssrc + (size_t)src * HH))[0];
    float4 s1 = ((const float4*)(ssrc + (size_t)src * HH))[1];
    float4 t0 = ((const float4*)(strg + (size_t)trg * HH))[0];
    float4 t1 = ((const float4*)(strg + (size_t)trg * HH))[1];
    float sc[8] = { s0.x + t0.x, s0.y + t0.y, s0.z + t0.z, s0.w + t0.w,
                    s1.x + t1.x, s1.y + t1.y, s1.z + t1.z, s1.w + t1.w };

    union { unsigned short u[8]; uint4 q; } o;
#pragma unroll
    for (int h = 0; h < 8; ++h) {
        float v = sc[h];
        v = v > 0.f ? v : 0.2f * v;            // leaky_relu(0.2)
        float ex = (m > 0.f) ? __expf(v) : 0.f;
        o.u[h] = f2bf(ex);
    }
    *(uint4*)(exb + (size_t)pos * HH) = o.q;   // 16B aligned (pos*8 shorts)
}

// ---------------------------------------------------------------------------
// Kernel D: one wave per target node; pure load+FMA inner loop (ex is
// precomputed). lo = cursor[node-1] (post-edge cursor = row end), hi = cursor[node].
// ---------------------------------------------------------------------------
__global__ __launch_bounds__(256) void k_gather(
    const int* __restrict__ cursor, const int* __restrict__ esrc,
    const unsigned short* __restrict__ exb,
    const unsigned short* __restrict__ proj, const float* __restrict__ bias,
    float* __restrict__ out)
{
    int gid  = blockIdx.x * 256 + threadIdx.x;
    int node = gid >> 6;
    int lane = gid & 63;
    if (node >= BN) return;
    int h = lane >> 3;
    int lo = node ? cursor[node - 1] : 0;
    int hi = cursor[node];

    float acc0 = 0.f, acc1 = 0.f, acc2 = 0.f, acc3 = 0.f, den = 0.f;
    int p = lo;
    for (; p + 8 <= hi; p += 8) {
        int s0 = esrc[p],     s1 = esrc[p + 1], s2 = esrc[p + 2], s3 = esrc[p + 3];
        int s4 = esrc[p + 4], s5 = esrc[p + 5], s6 = esrc[p + 6], s7 = esrc[p + 7];
        float e0 = bf2f(exb[(size_t)(p    ) * HH + h]);
        float e1 = bf2f(exb[(size_t)(p + 1) * HH + h]);
        float e2 = bf2f(exb[(size_t)(p + 2) * HH + h]);
        float e3 = bf2f(exb[(size_t)(p + 3) * HH + h]);
        float e4 = bf2f(exb[(size_t)(p + 4) * HH + h]);
        float e5 = bf2f(exb[(size_t)(p + 5) * HH + h]);
        float e6 = bf2f(exb[(size_t)(p + 6) * HH + h]);
        float e7 = bf2f(exb[(size_t)(p + 7) * HH + h]);
        ushort4 q0 = ((const ushort4*)(proj + (size_t)s0 * CC))[lane];
        ushort4 q1 = ((const ushort4*)(proj + (size_t)s1 * CC))[lane];
        ushort4 q2 = ((const ushort4*)(proj + (size_t)s2 * CC))[lane];
        ushort4 q3 = ((const ushort4*)(proj + (size_t)s3 * CC))[lane];
        ushort4 q4 = ((const ushort4*)(proj + (size_t)s4 * CC))[lane];
        ushort4 q5 = ((const ushort4*)(proj + (size_t)s5 * CC))[lane];
        ushort4 q6 = ((const ushort4*)(proj + (size_t)s6 * CC))[lane];
        ushort4 q7 = ((const ushort4*)(proj + (size_t)s7 * CC))[lane];
        den += ((e0 + e1) + (e2 + e3)) + ((e4 + e5) + (e6 + e7));
        acc0 += bf2f(q0.x)*e0 + bf2f(q1.x)*e1 + bf2f(q2.x)*e2 + bf2f(q3.x)*e3
              + bf2f(q4.x)*e4 + bf2f(q5.x)*e5 + bf2f(q6.x)*e6 + bf2f(q7.x)*e7;
        acc1 += bf2f(q0.y)*e0 + bf2f(q1.y)*e1 + bf2f(q2.y)*e2 + bf2f(q3.y)*e3
              + bf2f(q4.y)*e4 + bf2f(q5.y)*e5 + bf2f(q6.y)*e6 + bf2f(q7.y)*e7;
        acc2 += bf2f(q0.z)*e0 + bf2f(q1.z)*e1 + bf2f(q2.z)*e2 + bf2f(q3.z)*e3
              + bf2f(q4.z)*e4 + bf2f(q5.z)*e5 + bf2f(q6.z)*e6 + bf2f(q7.z)*e7;
        acc3 += bf2f(q0.w)*e0 + bf2f(q1.w)*e1 + bf2f(q2.w)*e2 + bf2f(q3.w)*e3
              + bf2f(q4.w)*e4 + bf2f(q5.w)*e5 + bf2f(q6.w)*e6 + bf2f(q7.w)*e7;
    }
    if (p + 4 <= hi) {
        int s0 = esrc[p], s1 = esrc[p + 1], s2 = esrc[p + 2], s3 = esrc[p + 3];
        float e0 = bf2f(exb[(size_t)(p    ) * HH + h]);
        float e1 = bf2f(exb[(size_t)(p + 1) * HH + h]);
        float e2 = bf2f(exb[(size_t)(p + 2) * HH + h]);
        float e3 = bf2f(exb[(size_t)(p + 3) * HH + h]);
        ushort4 q0 = ((const ushort4*)(proj + (size_t)s0 * CC))[lane];
        ushort4 q1 = ((const ushort4*)(proj + (size_t)s1 * CC))[lane];
        ushort4 q2 = ((const ushort4*)(proj + (size_t)s2 * CC))[lane];
        ushort4 q3 = ((const ushort4*)(proj + (size_t)s3 * CC))[lane];
        den += (e0 + e1) + (e2 + e3);
        acc0 += bf2f(q0.x)*e0 + bf2f(q1.x)*e1 + bf2f(q2.x)*e2 + bf2f(q3.x)*e3;
        acc1 += bf2f(q0.y)*e0 + bf2f(q1.y)*e1 + bf2f(q2.y)*e2 + bf2f(q3.y)*e3;
        acc2 += bf2f(q0.z)*e0 + bf2f(q1.z)*e1 + bf2f(q2.z)*e2 + bf2f(q3.z)*e3;
        acc3 += bf2f(q0.w)*e0 + bf2f(q1.w)*e1 + bf2f(q2.w)*e2 + bf2f(q3.w)*e3;
        p += 4;
    }
    for (; p < hi; ++p) {
        int s = esrc[p];
        float e = bf2f(exb[(size_t)p * HH + h]);
        ushort4 q = ((const ushort4*)(proj + (size_t)s * CC))[lane];
        den += e;
        acc0 += bf2f(q.x) * e;
        acc1 += bf2f(q.y) * e;
        acc2 += bf2f(q.z) * e;
        acc3 += bf2f(q.w) * e;
    }

    float inv = 1.f / (den + 1e-16f);
    float4 bv = ((const float4*)bias)[lane];
    float o0 = acc0 * inv + bv.x, o1 = acc1 * inv + bv.y;
    float o2 = acc2 * inv + bv.z, o3 = acc3 * inv + bv.w;
    o0 = o0 > 0.f ? o0 : __expf(o0) - 1.f;
    o1 = o1 > 0.f ? o1 : __expf(o1) - 1.f;
    o2 = o2 > 0.f ? o2 : __expf(o2) - 1.f;
    o3 = o3 > 0.f ? o3 : __expf(o3) - 1.f;
    ((float4*)(out + (size_t)node * CC))[lane] = make_float4(o0, o1, o2, o3);
}

// ---------------------------------------------------------------------------
extern "C" void kernel_launch(void* const* d_in, const int* in_sizes, int n_in,
                              void* d_out, int out_size, void* d_ws, size_t ws_size,
                              hipStream_t stream)
{
    const float* x     = (const float*)d_in[0];
    const int*   ei    = (const int*)  d_in[1];
    const float* mask  = (const float*)d_in[2];
    const float* Wm    = (const float*)d_in[3];
    const float* a_src = (const float*)d_in[4];
    const float* a_trg = (const float*)d_in[5];
    const float* bias  = (const float*)d_in[6];
    float* out = (float*)d_out;

    char* ws = (char*)d_ws;
    size_t off = 0;
    unsigned short* xb = (unsigned short*)(ws + off); off += (size_t)BN * FIN * 2; // 20.48 MB
    unsigned short* wb = (unsigned short*)(ws + off); off += (size_t)CC * FIN * 2; //  0.13 MB
    unsigned short* proj = (unsigned short*)(ws + off); off += (size_t)BN * CC * 2;// 20.48 MB
    float* ssrc = (float*)(ws + off); off += (size_t)BN * HH * 4;                  //  1.28 MB
    float* strg = (float*)(ws + off); off += (size_t)BN * HH * 4;                  //  1.28 MB
    int*   bsum = (int*)  (ws + off); off += 256 * 4;
    int*   boff = (int*)  (ws + off); off += 256 * 4;
    int*   deg    = (int*)(ws + off); off += (size_t)BN * 4;                       //  0.16 MB
    int*   cursor = (int*)(ws + off); off += (size_t)BN * 4;                       //  0.16 MB
    int*   esrc   = (int*)(ws + off); off += (size_t)BE * 4;                       //  2.56 MB
    // exb aliases xb: xb is dead after k_gemm; k_edge (the only writer of exb)
    // is stream-ordered after k_gemm. 10.24 MB < 20.48 MB.
    unsigned short* exb = xb;

    hipMemsetAsync(deg, 0, (size_t)BN * 4, stream);
    k_prep <<<XCVT + WCVT + CNTB, 256, 0, stream>>>(x, Wm, ei, xb, wb, deg);
    k_gemm <<<((BN + 127) / 128) * 2, 256, 0, stream>>>(xb, wb, proj);
    k_score<<<BN / 32, 256, 0, stream>>>(proj, a_src, a_trg, ssrc, strg);
    k_bsum <<<NB, 256, 0, stream>>>(deg, bsum);
    k_boff <<<1, 256, 0, stream>>>(bsum, boff);
    k_fill <<<NB, 256, 0, stream>>>(deg, boff, cursor);
    k_edge <<<(BE + 255) / 256, 256, 0, stream>>>(ei, mask, ssrc, strg,
                                                  cursor, esrc, exb);
    k_gather<<<(BN * 64) / 256, 256, 0, stream>>>(cursor, esrc, exb,
                                                  proj, bias, out);
}

// Round 7
// 146.352 us; speedup vs baseline: 17.7314x; 1.0315x over previous
//
#include <hip/hip_runtime.h>
#include <hip/hip_bf16.h>

#define BB   4
#define NN   10000
#define EE   160000
#define FIN  256
#define HH   8
#define FO   32
#define CC   256            // H*FO
#define BN   40000          // B*N
#define BE   640000         // B*E
#define NB   157            // ceil(BN/256)

#define XCVT 5000           // BN*FIN/8/256 blocks for x cvt
#define WCVT 32             // CC*FIN/8/256 blocks for W cvt
#define CNTB 625            // BE/4/256 blocks for histogram

typedef __attribute__((ext_vector_type(8))) __bf16 bf16x8;
typedef __attribute__((ext_vector_type(4))) float  f32x4;

__device__ __forceinline__ float bf2f(unsigned short u) {
    unsigned int v = ((unsigned int)u) << 16;
    return __uint_as_float(v);
}
__device__ __forceinline__ unsigned short f2bf(float f) {
    unsigned int u = __float_as_uint(f);
    u += 0x7fffu + ((u >> 16) & 1u);   // round-to-nearest-even
    return (unsigned short)(u >> 16);
}

__device__ __forceinline__ void cvt8(const float* __restrict__ src,
                                     unsigned short* __restrict__ dst, int i)
{
    const float4* s = (const float4*)src + (size_t)i * 2;
    float4 v0 = s[0], v1 = s[1];
    float f[8] = {v0.x, v0.y, v0.z, v0.w, v1.x, v1.y, v1.z, v1.w};
    union { unsigned short u[8]; uint4 q; } o;
#pragma unroll
    for (int j = 0; j < 8; ++j) o.u[j] = f2bf(f[j]);
    ((uint4*)dst)[i] = o.q;
}

// 256-thread block exclusive scan (int). lds4 is a __shared__ int[4].
__device__ __forceinline__ int block_excl_scan_256(int v, int t, int* lds4,
                                                   int* total)
{
    int lane = t & 63, wid = t >> 6;
    int incl = v;
#pragma unroll
    for (int off = 1; off < 64; off <<= 1) {
        int u = __shfl_up(incl, off);
        if (lane >= off) incl += u;
    }
    if (lane == 63) lds4[wid] = incl;
    __syncthreads();
    int w0 = lds4[0], w1 = lds4[1], w2 = lds4[2], w3 = lds4[3];
    int woff = (wid > 0 ? w0 : 0) + (wid > 1 ? w1 : 0) + (wid > 2 ? w2 : 0);
    *total = w0 + w1 + w2 + w3;
    return woff + incl - v;
}

// ---------------------------------------------------------------------------
// Kernel P: fused prep — cvt x->bf16, cvt W->bf16, deg histogram.
// ---------------------------------------------------------------------------
__global__ __launch_bounds__(256) void k_prep(
    const float* __restrict__ x, const float* __restrict__ Wm,
    const int* __restrict__ ei, unsigned short* __restrict__ xb,
    unsigned short* __restrict__ wb, int* __restrict__ deg)
{
    int blk = blockIdx.x, t = threadIdx.x;
    if (blk < XCVT) {
        cvt8(x, xb, blk * 256 + t);
    } else if (blk < XCVT + WCVT) {
        cvt8(Wm, wb, (blk - XCVT) * 256 + t);
    } else {
        int i = (blk - XCVT - WCVT) * 256 + t;      // 4 edges per thread
        int e0 = i * 4;
        int b  = e0 / EE;
        int le = e0 - b * EE;
        int4 tq = *(const int4*)(ei + (size_t)b * 2 * EE + EE + le);
        int base = b * NN;
        atomicAdd(&deg[tq.x + base], 1);
        atomicAdd(&deg[tq.y + base], 1);
        atomicAdd(&deg[tq.z + base], 1);
        atomicAdd(&deg[tq.w + base], 1);
    }
}

// ---------------------------------------------------------------------------
// Kernel 1: proj = xb @ Wb^T via MFMA bf16 (128x128 tile, BK=64, 4 waves)
// ---------------------------------------------------------------------------
__global__ __launch_bounds__(256) void k_gemm(
    const unsigned short* __restrict__ xb, const unsigned short* __restrict__ wb,
    unsigned short* __restrict__ proj)
{
    __shared__ alignas(16) unsigned short As[128 * 64];
    __shared__ alignas(16) unsigned short Bs[128 * 64];

    const int t    = threadIdx.x;
    const int lane = t & 63;
    const int wid  = t >> 6;
    const int wr   = wid >> 1, wc = wid & 1;
    const int bm   = blockIdx.x >> 1;
    const int bn   = blockIdx.x & 1;
    const int row0 = bm * 128, col0 = bn * 128;

    const int srow = t >> 3;
    const int scol = (t & 7) * 8;

    f32x4 acc[4][4] = {};

    for (int kt = 0; kt < 4; ++kt) {
        const int k0 = kt * 64;
#pragma unroll
        for (int p = 0; p < 4; ++p) {
            int tr = p * 32 + srow;
            int cg = scol ^ ((tr & 7) << 3);
            int gra = row0 + tr; if (gra > BN - 1) gra = BN - 1;
            const unsigned short* ga = xb + (size_t)gra * FIN + k0 + cg;
            const unsigned short* gb = wb + (size_t)(col0 + tr) * FIN + k0 + cg;
            __builtin_amdgcn_global_load_lds(
                (const __attribute__((address_space(1))) void*)ga,
                (__attribute__((address_space(3))) void*)&As[p * 2048 + t * 8],
                16, 0, 0);
            __builtin_amdgcn_global_load_lds(
                (const __attribute__((address_space(1))) void*)gb,
                (__attribute__((address_space(3))) void*)&Bs[p * 2048 + t * 8],
                16, 0, 0);
        }
        __syncthreads();

#pragma unroll
        for (int kk = 0; kk < 2; ++kk) {
            bf16x8 af[4], bfr[4];
#pragma unroll
            for (int m = 0; m < 4; ++m) {
                int row = wr * 64 + m * 16 + (lane & 15);
                int col = (kk * 32 + (lane >> 4) * 8) ^ ((row & 7) << 3);
                af[m] = *(const bf16x8*)&As[row * 64 + col];
            }
#pragma unroll
            for (int n = 0; n < 4; ++n) {
                int row = wc * 64 + n * 16 + (lane & 15);
                int col = (kk * 32 + (lane >> 4) * 8) ^ ((row & 7) << 3);
                bfr[n] = *(const bf16x8*)&Bs[row * 64 + col];
            }
#pragma unroll
            for (int m = 0; m < 4; ++m)
#pragma unroll
                for (int n = 0; n < 4; ++n)
                    acc[m][n] = __builtin_amdgcn_mfma_f32_16x16x32_bf16(
                        af[m], bfr[n], acc[m][n], 0, 0, 0);
        }
        __syncthreads();
    }

    const int rbase = row0 + wr * 64 + (lane >> 4) * 4;
    const int cbase = col0 + wc * 64 + (lane & 15);
#pragma unroll
    for (int m = 0; m < 4; ++m)
#pragma unroll
        for (int n = 0; n < 4; ++n)
#pragma unroll
            for (int j = 0; j < 4; ++j) {
                int r = rbase + m * 16 + j;
                int c = cbase + n * 16;
                if (r < BN) proj[(size_t)r * CC + c] = f2bf(acc[m][n][j]);
            }
}

// ---------------------------------------------------------------------------
// Kernel 2: per-node attention scores (node = blk*32 + t>>3, head = t&7)
// ---------------------------------------------------------------------------
__global__ __launch_bounds__(256) void k_score(
    const unsigned short* __restrict__ proj,
    const float* __restrict__ a_src, const float* __restrict__ a_trg,
    float* __restrict__ ssrc, float* __restrict__ strg)
{
    __shared__ float sa[CC], sb[CC];
    int t = threadIdx.x;
    sa[t] = a_src[t];
    sb[t] = a_trg[t];
    __syncthreads();
    int node = blockIdx.x * 32 + (t >> 3);
    int h    = t & 7;
    const uint4* q4 = (const uint4*)(proj + (size_t)node * CC + h * 32);
    const float* pa = sa + h * 32;
    const float* pb = sb + h * 32;
    float vs = 0.f, vt = 0.f;
#pragma unroll
    for (int i = 0; i < 4; ++i) {
        uint4 q = q4[i];
        unsigned int v[4] = {q.x, q.y, q.z, q.w};
#pragma unroll
        for (int j = 0; j < 4; ++j) {
            float lo = __uint_as_float(v[j] << 16);
            float hi = __uint_as_float(v[j] & 0xffff0000u);
            int c = i * 8 + j * 2;
            vs += lo * pa[c] + hi * pa[c + 1];
            vt += lo * pb[c] + hi * pb[c + 1];
        }
    }
    ssrc[(size_t)node * HH + h] = vs;
    strg[(size_t)node * HH + h] = vt;
}

// ---------------------------------------------------------------------------
// Scan pipeline: bsum -> boff -> fill. cursor[i] = CSR start; after k_edge,
// cursor[i] = CSR end (so row i spans [cursor[i-1], cursor[i])).
// ---------------------------------------------------------------------------
__global__ __launch_bounds__(256) void k_bsum(
    const int* __restrict__ deg, int* __restrict__ bsum)
{
    __shared__ int w4[4];
    int t = threadIdx.x, i = blockIdx.x * 256 + t;
    int v = (i < BN) ? deg[i] : 0;
#pragma unroll
    for (int off = 32; off >= 1; off >>= 1) v += __shfl_xor(v, off);
    if ((t & 63) == 0) w4[t >> 6] = v;
    __syncthreads();
    if (t == 0) bsum[blockIdx.x] = w4[0] + w4[1] + w4[2] + w4[3];
}

__global__ __launch_bounds__(256) void k_boff(
    const int* __restrict__ bsum, int* __restrict__ boff)
{
    __shared__ int w4[4];
    int t = threadIdx.x;
    int v = (t < NB) ? bsum[t] : 0;
    int total;
    int excl = block_excl_scan_256(v, t, w4, &total);
    if (t < NB) boff[t] = excl;
}

__global__ __launch_bounds__(256) void k_fill(
    const int* __restrict__ deg, const int* __restrict__ boff,
    int* __restrict__ cursor)
{
    __shared__ int w4[4];
    int t = threadIdx.x, i = blockIdx.x * 256 + t;
    int v = (i < BN) ? deg[i] : 0;
    int total;
    int excl = block_excl_scan_256(v, t, w4, &total);
    if (i < BN) cursor[i] = boff[blockIdx.x] + excl;
}

// ---------------------------------------------------------------------------
// Kernel C: 4 edges/thread, coalesced int4/float4 loads, 4 independent
// atomic chains; single 4B scattered store per edge (src | mask-bit).
// ---------------------------------------------------------------------------
__global__ __launch_bounds__(256) void k_edge(
    const int* __restrict__ ei, const float* __restrict__ mask,
    int* __restrict__ cursor, int* __restrict__ esrc)
{
    int i = blockIdx.x * 256 + threadIdx.x;     // [0, BE/4)
    if (i >= BE / 4) return;
    int e0 = i * 4;
    int b  = e0 / EE;                            // EE%4==0 -> uniform batch
    int le = e0 - b * EE;
    const int* eb = ei + (size_t)b * 2 * EE;
    int4   sq = *(const int4*)(eb + le);
    int4   tq = *(const int4*)(eb + EE + le);
    float4 mq = *(const float4*)(mask + e0);
    int base = b * NN;

    int p0 = atomicAdd(&cursor[tq.x + base], 1);
    int p1 = atomicAdd(&cursor[tq.y + base], 1);
    int p2 = atomicAdd(&cursor[tq.z + base], 1);
    int p3 = atomicAdd(&cursor[tq.w + base], 1);
    esrc[p0] = (sq.x + base) | (mq.x > 0.f ? 0 : (int)0x80000000);
    esrc[p1] = (sq.y + base) | (mq.y > 0.f ? 0 : (int)0x80000000);
    esrc[p2] = (sq.z + base) | (mq.z > 0.f ? 0 : (int)0x80000000);
    esrc[p3] = (sq.w + base) | (mq.w > 0.f ? 0 : (int)0x80000000);
}

// ---------------------------------------------------------------------------
// Kernel D: one wave per target node, 8 edges per step. Lane l computes the
// exp for (edge l&7, head l>>3) -- exactly one exp per (edge,head) chip-wide
// -- then __shfl distributes. Accumulate unnorm. sums, normalize, bias+ELU.
// ---------------------------------------------------------------------------
__global__ __launch_bounds__(256) void k_gather(
    const int* __restrict__ cursor, const int* __restrict__ esrc,
    const float* __restrict__ ssrc, const float* __restrict__ strg,
    const unsigned short* __restrict__ proj, const float* __restrict__ bias,
    float* __restrict__ out)
{
    int gid  = blockIdx.x * 256 + threadIdx.x;
    int node = gid >> 6;
    int lane = gid & 63;
    if (node >= BN) return;
    int h  = lane >> 3;                 // head for this lane's output columns
    int el = lane & 7;                  // edge slot this lane computes exp for
    int hb = lane & 56;                 // 8*h
    float st = strg[(size_t)node * HH + h];
    int lo = node ? cursor[node - 1] : 0;
    int hi = cursor[node];

    float acc0 = 0.f, acc1 = 0.f, acc2 = 0.f, acc3 = 0.f, den = 0.f;

    for (int p = lo; p < hi; p += 8) {
        int idx  = p + el;
        bool vld = idx < hi;
        int sv   = esrc[vld ? idx : lo];           // clamp: valid row, ex=0
        int s    = sv & 0x7fffffff;
        float sc = ssrc[(size_t)s * HH + h] + st;  // score for (edge el, head h)
        sc = sc > 0.f ? sc : 0.2f * sc;            // leaky_relu(0.2)
        float ex = (vld && sv >= 0) ? __expf(sc) : 0.f;

#pragma unroll
        for (int e = 0; e < 8; ++e) {
            float ee = __shfl(ex, e | hb);         // (edge e, this lane's head)
            int   se = __shfl(s, e);               // edge e's src node
            ushort4 q = ((const ushort4*)(proj + (size_t)se * CC))[lane];
            den  += ee;
            acc0 += bf2f(q.x) * ee;
            acc1 += bf2f(q.y) * ee;
            acc2 += bf2f(q.z) * ee;
            acc3 += bf2f(q.w) * ee;
        }
    }

    float inv = 1.f / (den + 1e-16f);
    float4 bv = ((const float4*)bias)[lane];
    float o0 = acc0 * inv + bv.x, o1 = acc1 * inv + bv.y;
    float o2 = acc2 * inv + bv.z, o3 = acc3 * inv + bv.w;
    o0 = o0 > 0.f ? o0 : __expf(o0) - 1.f;
    o1 = o1 > 0.f ? o1 : __expf(o1) - 1.f;
    o2 = o2 > 0.f ? o2 : __expf(o2) - 1.f;
    o3 = o3 > 0.f ? o3 : __expf(o3) - 1.f;
    ((float4*)(out + (size_t)node * CC))[lane] = make_float4(o0, o1, o2, o3);
}

// ---------------------------------------------------------------------------
extern "C" void kernel_launch(void* const* d_in, const int* in_sizes, int n_in,
                              void* d_out, int out_size, void* d_ws, size_t ws_size,
                              hipStream_t stream)
{
    const float* x     = (const float*)d_in[0];
    const int*   ei    = (const int*)  d_in[1];
    const float* mask  = (const float*)d_in[2];
    const float* Wm    = (const float*)d_in[3];
    const float* a_src = (const float*)d_in[4];
    const float* a_trg = (const float*)d_in[5];
    const float* bias  = (const float*)d_in[6];
    float* out = (float*)d_out;

    char* ws = (char*)d_ws;
    size_t off = 0;
    unsigned short* xb = (unsigned short*)(ws + off); off += (size_t)BN * FIN * 2; // 20.48 MB
    unsigned short* wb = (unsigned short*)(ws + off); off += (size_t)CC * FIN * 2; //  0.13 MB
    unsigned short* proj = (unsigned short*)(ws + off); off += (size_t)BN * CC * 2;// 20.48 MB
    float* ssrc = (float*)(ws + off); off += (size_t)BN * HH * 4;                  //  1.28 MB
    float* strg = (float*)(ws + off); off += (size_t)BN * HH * 4;                  //  1.28 MB
    int*   bsum = (int*)  (ws + off); off += 256 * 4;
    int*   boff = (int*)  (ws + off); off += 256 * 4;
    int*   deg    = (int*)(ws + off); off += (size_t)BN * 4;                       //  0.16 MB
    int*   cursor = (int*)(ws + off); off += (size_t)BN * 4;                       //  0.16 MB
    int*   esrc   = (int*)(ws + off); off += (size_t)BE * 4;                       //  2.56 MB

    hipMemsetAsync(deg, 0, (size_t)BN * 4, stream);
    k_prep <<<XCVT + WCVT + CNTB, 256, 0, stream>>>(x, Wm, ei, xb, wb, deg);
    k_gemm <<<((BN + 127) / 128) * 2, 256, 0, stream>>>(xb, wb, proj);
    k_score<<<BN / 32, 256, 0, stream>>>(proj, a_src, a_trg, ssrc, strg);
    k_bsum <<<NB, 256, 0, stream>>>(deg, bsum);
    k_boff <<<1, 256, 0, stream>>>(bsum, boff);
    k_fill <<<NB, 256, 0, stream>>>(deg, boff, cursor);
    k_edge <<<(BE / 4 + 255) / 256, 256, 0, stream>>>(ei, mask, cursor, esrc);
    k_gather<<<(BN * 64) / 256, 256, 0, stream>>>(cursor, esrc, ssrc, strg,
                                                  proj, bias, out);
}